// Round 15
// baseline (519.904 us; speedup 1.0000x reference)
//
#include <hip/hip_runtime.h>
#include <cstddef>

#define NPIX 65536
#define PI_F 3.14159265358979323846f

typedef float v4f __attribute__((ext_vector_type(4)));
typedef short v8s __attribute__((ext_vector_type(8)));
typedef unsigned short u16;

__device__ __forceinline__ void cacc(float2& acc, float2 a, float2 b) {
  acc.x = fmaf(a.x, b.x, fmaf(-a.y, b.y, acc.x));
  acc.y = fmaf(a.x, b.y, fmaf(a.y, b.x, acc.y));
}
__device__ __forceinline__ float2 cmulf(float2 a, float2 b) {
  return make_float2(a.x*b.x - a.y*b.y, a.x*b.y + a.y*b.x);
}
__device__ __forceinline__ float2 add2(float2 a, float2 b) { return make_float2(a.x+b.x, a.y+b.y); }
__device__ __forceinline__ float2 sub2(float2 a, float2 b) { return make_float2(a.x-b.x, a.y-b.y); }
__device__ __forceinline__ float2 shflc(float2 v, int mask) {
  return make_float2(__shfl_xor(v.x, mask), __shfl_xor(v.y, mask));
}
// non-temporal 8-byte store of a float2 (keeps dwordx2 width, adds nt flag)
__device__ __forceinline__ void nts2(float2* p, float2 v) {
  __builtin_nontemporal_store(*reinterpret_cast<const double*>(&v),
                              reinterpret_cast<double*>(p));
}
__device__ __forceinline__ void nts1(float* p, float v) {
  __builtin_nontemporal_store(v, p);
}
// split fp32 into bf16 hi (truncated) + bf16 lo of residual
__device__ __forceinline__ void bf16split(float v, u16& h, u16& l) {
  unsigned bits = __float_as_uint(v);
  h = (u16)(bits >> 16);
  float r = v - __uint_as_float((unsigned)h << 16);
  l = (u16)(__float_as_uint(r) >> 16);
}
// 8 per-lane twiddles: idx = {l, 64+l, 2l, (l&31)<<2, (l&15)<<3, (l&7)<<4, (l&3)<<5, (l&1)<<6}
__device__ __forceinline__ void make_tw(float sgn, int l, float2* tw) {
  const float c = sgn * (2.0f*PI_F/256.0f);
  int idxs[8] = { l, 64+l, 2*l, (l&31)<<2, (l&15)<<3, (l&7)<<4, (l&3)<<5, (l&1)<<6 };
  #pragma unroll
  for (int r = 0; r < 8; ++r) { float sn, cs; __sincosf(c*idxs[r], &sn, &cs); tw[r] = make_float2(cs, sn); }
}
__device__ __forceinline__ void fwd_stage(float2& vv, int lane, int H, float2 tws, bool unit) {
  float2 p = shflc(vv, H);
  bool up = (lane & H) != 0;
  float2 lo = add2(vv, p);
  float2 df = sub2(p, vv);
  float2 hi = unit ? df : cmulf(df, tws);
  vv = up ? hi : lo;
}
__device__ __forceinline__ void inv_stage(float2& vv, int lane, int H, float2 tws, bool unit) {
  float2 p = shflc(vv, H);
  bool up = (lane & H) != 0;
  float2 bv = up ? vv : p;
  float2 av = up ? p : vv;
  float2 t = unit ? bv : cmulf(bv, tws);
  vv = up ? sub2(av, t) : add2(av, t);
}
__device__ __forceinline__ void ifft256_reg(float2& v0, float2& v1, float2& v2,
    float2& v3, int lane, const float2* tw) {
  inv_stage(v0, lane, 1, tw[0], true ); inv_stage(v1, lane, 1, tw[0], true );
  inv_stage(v2, lane, 1, tw[0], true ); inv_stage(v3, lane, 1, tw[0], true );
  inv_stage(v0, lane, 2, tw[7], false); inv_stage(v1, lane, 2, tw[7], false);
  inv_stage(v2, lane, 2, tw[7], false); inv_stage(v3, lane, 2, tw[7], false);
  inv_stage(v0, lane, 4, tw[6], false); inv_stage(v1, lane, 4, tw[6], false);
  inv_stage(v2, lane, 4, tw[6], false); inv_stage(v3, lane, 4, tw[6], false);
  inv_stage(v0, lane, 8, tw[5], false); inv_stage(v1, lane, 8, tw[5], false);
  inv_stage(v2, lane, 8, tw[5], false); inv_stage(v3, lane, 8, tw[5], false);
  inv_stage(v0, lane, 16, tw[4], false); inv_stage(v1, lane, 16, tw[4], false);
  inv_stage(v2, lane, 16, tw[4], false); inv_stage(v3, lane, 16, tw[4], false);
  inv_stage(v0, lane, 32, tw[3], false); inv_stage(v1, lane, 32, tw[3], false);
  inv_stage(v2, lane, 32, tw[3], false); inv_stage(v3, lane, 32, tw[3], false);
  { float2 t01 = cmulf(v1, tw[2]); float2 n0 = add2(v0, t01), n1 = sub2(v0, t01);
    float2 t23 = cmulf(v3, tw[2]); float2 n2 = add2(v2, t23), n3 = sub2(v2, t23);
    v0 = n0; v1 = n1; v2 = n2; v3 = n3; }
  { float2 t02 = cmulf(v2, tw[0]); float2 n0 = add2(v0, t02), n2 = sub2(v0, t02);
    float2 t13 = cmulf(v3, tw[1]); float2 n1 = add2(v1, t13), n3 = sub2(v1, t13);
    v0 = n0; v2 = n2; v1 = n1; v3 = n3; }
}

// ---------------- setup: A1, A2T, A2L (brev-x domain), E1, E2 ---------------
__global__ __launch_bounds__(256) void k_setup(const float2* __restrict__ p1,
    const float2* __restrict__ p2, const float* __restrict__ txv,
    const float* __restrict__ tyv, float2* __restrict__ A1,
    float2* __restrict__ A2T, float2* __restrict__ A2L,
    float2* __restrict__ E1, float2* __restrict__ E2) {
  int gid = blockIdx.x*256 + threadIdx.x;          // [0, 524288)
  int o = gid & 255, p = (gid>>8)&7, k = (gid>>11)&15, i = gid>>15;
  float ko = (o < 128) ? (float)o : (float)(o - 256);
  float dty = tyv[1] - tyv[0];
  float dtx = txv[1] - txv[0];
  const float TWO_PI = 6.283185307179586f;
  {
    float lam = TWO_PI * ko / (256.0f * dty);
    float2 pv = p1[(i*16+k)*8 + p];
    float xr = -pv.x, yi = lam - pv.y;
    float D = xr*xr + yi*yi;
    A1[((size_t)((i*16+k)*8 + p))*256 + o] = make_float2(xr/D, -yi/D);
    float tv = tyv[o];
    float m = expf(pv.x*tv);
    E1[((size_t)((i*16+k)*8 + p))*256 + o] = make_float2(m*cosf(pv.y*tv), m*sinf(pv.y*tv));
  }
  {
    // x-axis of the spectral domain is bit-reverse permuted (row FFT is DIF)
    int fo = __brev((unsigned)o) >> 24;
    float ko2 = (fo < 128) ? (float)fo : (float)(fo - 256);
    float lam = TWO_PI * ko2 / (256.0f * dtx);
    float2 pv = p2[(i*16+k)*8 + p];
    float xr = -pv.x, yi = lam - pv.y;
    float D = xr*xr + yi*yi;
    float2 val = make_float2(xr/D, -yi/D);
    A2T[((size_t)i*256 + o)*128 + k*8 + p] = val;
    A2L[((size_t)((i*16+k)*8 + p))*256 + o] = val;
    float tv = txv[o];                 // E2 lives in real space: natural order
    float m = expf(pv.x*tv);
    E2[((size_t)((i*16+k)*8 + p))*256 + o] = make_float2(m*cosf(pv.y*tv), m*sinf(pv.y*tv));
  }
}

// ---- build BT_big (bf16 hi/lo) from A2T:  BT[i][n2][k2], k2 in [0,512) -----
__global__ __launch_bounds__(256) void k_B(const float2* __restrict__ A2T,
    u16* __restrict__ BH, u16* __restrict__ BL) {
  int bid = blockIdx.x;               // i*8 + g
  int i = bid >> 3, g = bid & 7;
  int tid = threadIdx.x;
  int n2 = g*32 + (tid >> 3);
  int kq = n2 >> 1, par = n2 & 1;
  int x0 = (tid & 7) * 32;
  size_t outb = ((size_t)i*256 + n2)*512;
  for (int xx = 0; xx < 32; ++xx) {
    int x = x0 + xx;
    float2 a2 = A2T[((size_t)i*256 + x)*128 + kq];
    float v0 = par ? a2.y : a2.x;       // k2 = 2x
    float v1 = par ? a2.x : -a2.y;      // k2 = 2x+1
    u16 h0, l0, h1, l1;
    bf16split(v0, h0, l0);
    bf16split(v1, h1, l1);
    BH[outb + 2*x]     = h0;  BL[outb + 2*x]     = l0;
    BH[outb + 2*x + 1] = h1;  BL[outb + 2*x + 1] = l1;
  }
}

// ---------------- T[ik][q][o] = sum_p res[ik][p][q] A1[ik][p][o] ------------
__global__ __launch_bounds__(256) void k_T(const float2* __restrict__ res,
    const float2* __restrict__ A1, float2* __restrict__ Tt) {
  int ik = blockIdx.x, tid = threadIdx.x;
  __shared__ float2 rbuf[64];
  __shared__ float2 a1[8][256];
  if (tid < 64) rbuf[tid] = res[(size_t)ik*64 + tid];
  for (int e = 0; e < 8; ++e) {
    int lin = tid + 256*e;
    int p = lin >> 8, o = lin & 255;
    a1[p][o] = A1[((size_t)ik*8 + p)*256 + o];
  }
  __syncthreads();
  int o = tid;
  #pragma unroll
  for (int q = 0; q < 8; ++q) {
    float2 acc = make_float2(0.f, 0.f);
    #pragma unroll
    for (int p = 0; p < 8; ++p) cacc(acc, rbuf[p*8+q], a1[p][o]);
    Tt[((size_t)ik*8 + q)*256 + o] = acc;
  }
}

// ---- stats partials of v (recomputed from x), 8 segments per img -----------
__global__ __launch_bounds__(256) void k_stats_v_part(const float* __restrict__ x,
    const float* __restrict__ fc0w, const float* __restrict__ fc0b,
    float2* __restrict__ part) {
  int bid = blockIdx.x;               // img*8 + seg
  int seg = bid & 7, img = bid >> 3;
  int k = img & 15, b = img >> 4;
  int tid = threadIdx.x;
  float w0 = fc0w[k], w1 = fc0w[16+k], w2 = fc0w[32+k], w3 = fc0w[48+k], w4 = fc0w[64+k];
  float base = fc0b[k] + (tid*(1.0f/255.0f))*w4;
  const float* xb = x + (size_t)b*3*NPIX + (size_t)seg*8192;
  float s = 0.f, s2 = 0.f;
  for (int it = 0; it < 32; ++it) {
    int row = seg*32 + it;
    int p = it*256 + tid;
    float val = base + (row*(1.0f/255.0f))*w3 + xb[p]*w0 + xb[NPIX+p]*w1 + xb[2*NPIX+p]*w2;
    s += val; s2 += val*val;
  }
  __shared__ float rs[256], rq[256];
  rs[tid] = s; rq[tid] = s2;
  __syncthreads();
  for (int off = 128; off > 0; off >>= 1) {
    if (tid < off) { rs[tid] += rs[tid+off]; rq[tid] += rq[tid+off]; }
    __syncthreads();
  }
  if (tid == 0) part[bid] = make_float2(rs[0], rq[0]);
}

// ---- stats partials of a real plane buffer ---------------------------------
__global__ __launch_bounds__(256) void k_stats_p_part(const float* __restrict__ v,
    float2* __restrict__ part) {
  int bid = blockIdx.x;               // img*8 + seg
  int seg = bid & 7, img = bid >> 3;
  int tid = threadIdx.x;
  const float* p = v + (size_t)img*NPIX + (size_t)seg*8192;
  float s = 0.f, s2 = 0.f;
  for (int it = 0; it < 32; ++it) { float a = p[it*256 + tid]; s += a; s2 += a*a; }
  __shared__ float rs[256], rq[256];
  rs[tid] = s; rq[tid] = s2;
  __syncthreads();
  for (int off = 128; off > 0; off >>= 1) {
    if (tid < off) { rs[tid] += rs[tid+off]; rq[tid] += rq[tid+off]; }
    __syncthreads();
  }
  if (tid == 0) part[bid] = make_float2(rs[0], rq[0]);
}

// ---- combine 8 partials per img -> stats -----------------------------------
__global__ __launch_bounds__(256) void k_stats_fin(const float2* __restrict__ part,
    float2* __restrict__ stats, int nimg) {
  int img = blockIdx.x*256 + threadIdx.x;
  if (img >= nimg) return;
  float s = 0.f, s2 = 0.f;
  #pragma unroll
  for (int e = 0; e < 8; ++e) { float2 v = part[img*8 + e]; s += v.x; s2 += v.y; }
  float mean = s * (1.0f/65536.0f);
  float var  = s2 * (1.0f/65536.0f) - mean*mean;
  stats[img] = make_float2(mean, rsqrtf(var + 1e-5f));
}

// ---- row FFT of normalized v (recomputed from x), in-register DIF ----------
__global__ __launch_bounds__(256) void k_fft_v(const float* __restrict__ x,
    const float* __restrict__ fc0w, const float* __restrict__ fc0b,
    const float2* __restrict__ stats, float2* __restrict__ out) {
  int tid = threadIdx.x, lane = tid & 63, rowi = tid >> 6;
  int bid = blockIdx.x;                  // [0, 8192)
  int img = bid >> 6;
  int h   = (bid & 63)*4 + rowi;
  int k = img & 15, b = img >> 4;
  float2 st = stats[img];
  float w0 = fc0w[k], w1 = fc0w[16+k], w2 = fc0w[32+k], w3 = fc0w[48+k], w4 = fc0w[64+k];
  float bb = fc0b[k] + (h*(1.0f/255.0f))*w3;
  const float* xb = x + (size_t)b*3*NPIX + (size_t)h*256;
  float2 tw[8];
  make_tw(-1.0f, lane, tw);
  float2 v0, v1, v2, v3;
  {
    #pragma unroll
    for (int e = 0; e < 4; ++e) {
      int j = e*64 + lane;
      float val = bb + (j*(1.0f/255.0f))*w4 + xb[j]*w0 + xb[NPIX+j]*w1 + xb[2*NPIX+j]*w2;
      val = (val - st.x)*st.y;
      float2 c = make_float2(val, 0.f);
      if (e == 0) v0 = c; else if (e == 1) v1 = c; else if (e == 2) v2 = c; else v3 = c;
    }
  }
  { float2 n0 = add2(v0, v2), n2 = cmulf(sub2(v0, v2), tw[0]);
    float2 n1 = add2(v1, v3), n3 = cmulf(sub2(v1, v3), tw[1]);
    v0 = n0; v1 = n1; v2 = n2; v3 = n3; }
  { float2 n0 = add2(v0, v1), n1 = cmulf(sub2(v0, v1), tw[2]);
    float2 n2 = add2(v2, v3), n3 = cmulf(sub2(v2, v3), tw[2]);
    v0 = n0; v1 = n1; v2 = n2; v3 = n3; }
  fwd_stage(v0, lane, 32, tw[3], false); fwd_stage(v1, lane, 32, tw[3], false);
  fwd_stage(v2, lane, 32, tw[3], false); fwd_stage(v3, lane, 32, tw[3], false);
  fwd_stage(v0, lane, 16, tw[4], false); fwd_stage(v1, lane, 16, tw[4], false);
  fwd_stage(v2, lane, 16, tw[4], false); fwd_stage(v3, lane, 16, tw[4], false);
  fwd_stage(v0, lane,  8, tw[5], false); fwd_stage(v1, lane,  8, tw[5], false);
  fwd_stage(v2, lane,  8, tw[5], false); fwd_stage(v3, lane,  8, tw[5], false);
  fwd_stage(v0, lane,  4, tw[6], false); fwd_stage(v1, lane,  4, tw[6], false);
  fwd_stage(v2, lane,  4, tw[6], false); fwd_stage(v3, lane,  4, tw[6], false);
  fwd_stage(v0, lane,  2, tw[7], false); fwd_stage(v1, lane,  2, tw[7], false);
  fwd_stage(v2, lane,  2, tw[7], false); fwd_stage(v3, lane,  2, tw[7], false);
  fwd_stage(v0, lane,  1, tw[0], true ); fwd_stage(v1, lane,  1, tw[0], true );
  fwd_stage(v2, lane,  1, tw[0], true ); fwd_stage(v3, lane,  1, tw[0], true );
  float2* op = out + ((size_t)img*256 + h)*256;
  nts2(&op[lane], v0); nts2(&op[64+lane], v1);
  nts2(&op[128+lane], v2); nts2(&op[192+lane], v3);
}

// ---- forward column FFT, writes o-major alphaR[o][img][x] ------------------
__global__ __launch_bounds__(256) void k_fft_colR(const float2* __restrict__ in,
    float2* __restrict__ outp) {
  __shared__ float tr[256][17], tim[256][17];
  __shared__ float twr[128], twi[128];
  int tid = threadIdx.x;
  int c = tid & 15, g = tid >> 4;
  int img = blockIdx.x >> 4;
  int c0  = (blockIdx.x & 15) * 16;
  if (tid < 128) {
    float ang = (PI_F/128.0f)*tid;
    twr[tid] = cosf(ang); twi[tid] = -sinf(ang);
  }
  const float2* base = in + (size_t)img*NPIX + c0;
  #pragma unroll
  for (int it = 0; it < 16; ++it) {
    int row = it*16 + g;
    float2 v = base[(size_t)row*256 + c];
    int br = __brev((unsigned)row) >> 24;
    tr[br][c] = v.x; tim[br][c] = v.y;
  }
  __syncthreads();
  int lane = tid & 63, w = tid >> 6;
  int cw = w*4 + (lane >> 4);
  int gw = lane & 15;
  for (int s = 0; s < 8; ++s) {
    __builtin_amdgcn_wave_barrier();
    int half = 1 << s;
    #pragma unroll
    for (int r = 0; r < 8; ++r) {
      int m  = gw + 16*r;
      int t  = m & (half - 1);
      int grp = m >> s;
      int i0 = (grp << (s+1)) + t;
      int i1 = i0 + half;
      int twx = t << (7 - s);
      float wr = twr[twx], wi = twi[twx];
      float br = tr[i1][cw], bi = tim[i1][cw];
      float vr = br*wr - bi*wi, vi = br*wi + bi*wr;
      float ar = tr[i0][cw], ai = tim[i0][cw];
      tr[i0][cw] = ar + vr; tim[i0][cw] = ai + vi;
      tr[i1][cw] = ar - vr; tim[i1][cw] = ai - vi;
    }
  }
  __syncthreads();
  #pragma unroll
  for (int it = 0; it < 16; ++it) {
    int row = it*16 + g;
    float2 vv = make_float2(tr[row][c], tim[row][c]);
    nts2(&outp[((size_t)row*128 + img)*256 + c0 + c], vv);
  }
}

// ---------------- column inverse FFT, write real part to out ---------------
__global__ __launch_bounds__(256) void k_ifft_col_real(const float2* __restrict__ in,
    float* __restrict__ outp, float scale) {
  __shared__ float tr[256][17], tim[256][17];
  __shared__ float twr[128], twi[128];
  int tid = threadIdx.x;
  int c = tid & 15, g = tid >> 4;
  int img = blockIdx.x >> 4;
  int c0  = (blockIdx.x & 15) * 16;
  if (tid < 128) {
    float ang = (PI_F/128.0f)*tid;
    twr[tid] = cosf(ang); twi[tid] = sinf(ang);
  }
  const float2* base = in + (size_t)img*NPIX + c0;
  #pragma unroll
  for (int it = 0; it < 16; ++it) {
    int row = it*16 + g;
    float2 v = base[(size_t)row*256 + c];
    int br = __brev((unsigned)row) >> 24;
    tr[br][c] = v.x; tim[br][c] = v.y;
  }
  __syncthreads();
  int lane = tid & 63, w = tid >> 6;
  int cw = w*4 + (lane >> 4);
  int gw = lane & 15;
  for (int s = 0; s < 8; ++s) {
    __builtin_amdgcn_wave_barrier();
    int half = 1 << s;
    #pragma unroll
    for (int r = 0; r < 8; ++r) {
      int m  = gw + 16*r;
      int t  = m & (half - 1);
      int grp = m >> s;
      int i0 = (grp << (s+1)) + t;
      int i1 = i0 + half;
      int twx = t << (7 - s);
      float wr = twr[twx], wi = twi[twx];
      float br = tr[i1][cw], bi = tim[i1][cw];
      float vr = br*wr - bi*wi, vi = br*wi + bi*wr;
      float ar = tr[i0][cw], ai = tim[i0][cw];
      tr[i0][cw] = ar + vr; tim[i0][cw] = ai + vi;
      tr[i1][cw] = ar - vr; tim[i1][cw] = ai - vi;
    }
  }
  __syncthreads();
  float* ob = outp + (size_t)img*NPIX + c0;
  #pragma unroll
  for (int it = 0; it < 16; ++it) {
    int row = it*16 + g;
    nts1(&ob[(size_t)row*256 + c], tr[row][c]*scale);
  }
}

// ---- MFMA S-GEMM: per i, S_real[M=2048][N=256] = A_real[M][512] x B[512][256]
__global__ __launch_bounds__(256) void k_Smm(const float2* __restrict__ alphaR,
    const u16* __restrict__ BH, const u16* __restrict__ BL,
    float* __restrict__ Sf) {
  __shared__ u16 Ah[128][40], Al[128][40], Bhs[128][40], Bls[128][40];
  int bid = blockIdx.x;               // i*32 + mt*2 + nt
  int i = bid >> 5, rem = bid & 31, mt = rem >> 1, nt = rem & 1;
  int tid = threadIdx.x;
  int lane = tid & 63, wid = tid >> 6, wr = wid >> 1, wc = wid & 1;
  int r2 = tid >> 1, h2 = tid & 1;
  int m_s = mt*128 + r2;
  const float2* arow = alphaR + ((size_t)((m_s & 255)*128) + (size_t)((m_s >> 8)*16 + i))*256 + h2*8;
  const u16* bhrow = BH + ((size_t)i*256 + nt*128 + r2)*512 + h2*16;
  const u16* blrow = BL + ((size_t)i*256 + nt*128 + r2)*512 + h2*16;
  v4f acc[4][4];
  #pragma unroll
  for (int a = 0; a < 4; ++a)
    #pragma unroll
    for (int b = 0; b < 4; ++b) acc[a][b] = (v4f){0.f, 0.f, 0.f, 0.f};
  for (int kc = 0; kc < 16; ++kc) {
    const float2* ap = arow + kc*16;
    #pragma unroll
    for (int e = 0; e < 8; ++e) {
      float2 v = ap[e];
      u16 hr, lr, hi_, li_;
      bf16split(v.x, hr, lr);
      bf16split(v.y, hi_, li_);
      int c = h2*16 + 2*e;
      Ah[r2][c] = hr; Ah[r2][c+1] = hi_;
      Al[r2][c] = lr; Al[r2][c+1] = li_;
    }
    {
      const uint4* ph = (const uint4*)(bhrow + (size_t)kc*32);
      uint4 q0 = ph[0], q1 = ph[1];
      *((uint4*)&Bhs[r2][h2*16])     = q0;
      *((uint4*)&Bhs[r2][h2*16 + 8]) = q1;
      const uint4* pl = (const uint4*)(blrow + (size_t)kc*32);
      uint4 s0 = pl[0], s1 = pl[1];
      *((uint4*)&Bls[r2][h2*16])     = s0;
      *((uint4*)&Bls[r2][h2*16 + 8]) = s1;
    }
    __syncthreads();
    v8s af_h[4], af_l[4];
    int c8 = (lane >> 4) * 8;
    #pragma unroll
    for (int fi = 0; fi < 4; ++fi) {
      int row = wr*64 + fi*16 + (lane & 15);
      af_h[fi] = *(const v8s*)&Ah[row][c8];
      af_l[fi] = *(const v8s*)&Al[row][c8];
    }
    #pragma unroll
    for (int fj = 0; fj < 4; ++fj) {
      int row = wc*64 + fj*16 + (lane & 15);
      v8s bh_f = *(const v8s*)&Bhs[row][c8];
      v8s bl_f = *(const v8s*)&Bls[row][c8];
      #pragma unroll
      for (int fi = 0; fi < 4; ++fi) {
        acc[fi][fj] = __builtin_amdgcn_mfma_f32_16x16x32_bf16(af_h[fi], bh_f, acc[fi][fj], 0, 0, 0);
        acc[fi][fj] = __builtin_amdgcn_mfma_f32_16x16x32_bf16(af_l[fi], bh_f, acc[fi][fj], 0, 0, 0);
        acc[fi][fj] = __builtin_amdgcn_mfma_f32_16x16x32_bf16(af_h[fi], bl_f, acc[fi][fj], 0, 0, 0);
      }
    }
    __syncthreads();
  }
  #pragma unroll
  for (int fi = 0; fi < 4; ++fi) {
    #pragma unroll
    for (int rr = 0; rr < 4; ++rr) {
      int m = mt*128 + wr*64 + fi*16 + (lane >> 4)*4 + rr;
      int n = m >> 8, o = m & 255;
      float* srow = Sf + ((size_t)(n*16 + i)*256 + o)*256 + nt*128 + wc*64 + (lane & 15);
      #pragma unroll
      for (int fj = 0; fj < 4; ++fj)
        nts1(&srow[fj*16], acc[fi][fj][rr]);
    }
  }
}

// ---------------- Mt[n,i,k,p,q] = sum_o S[n,i,o,(k,q)] A1[i,k,p,o] ----------
__global__ __launch_bounds__(256) void k_Mt(const float2* __restrict__ S,
    const float2* __restrict__ A1, float2* __restrict__ Mt) {
  __shared__ float2 sl[8][258];
  __shared__ float2 a1l[8][258];
  __shared__ float2 part[4][64];
  int bid = blockIdx.x;               // (n*16+i)*16 + k
  int k = bid & 15, ni = bid >> 4;
  int i = ni & 15;
  int ik = i*16 + k;
  int tid = threadIdx.x;
  for (int e = 0; e < 8; ++e) {
    int lin = tid + 256*e;            // 0..2047
    int o = lin >> 3, q = lin & 7;
    sl[q][o] = S[((size_t)ni*256 + o)*128 + k*8 + q];
  }
  for (int e = 0; e < 8; ++e) {
    int lin = tid + 256*e;
    int p = lin >> 8, o = lin & 255;
    a1l[p][o] = A1[((size_t)ik*8 + p)*256 + o];
  }
  __syncthreads();
  int oq = tid >> 6, pq = tid & 63, p = pq >> 3, q = pq & 7;
  float2 acc = make_float2(0.f, 0.f);
  int o0 = oq*64;
  for (int o = o0; o < o0 + 64; ++o) cacc(acc, sl[q][o], a1l[p][o]);
  part[oq][pq] = acc;
  __syncthreads();
  if (oq == 0) {
    float2 a = part[0][pq], b = part[1][pq], c = part[2][pq], d = part[3][pq];
    acc.x = a.x + b.x + c.x + d.x;
    acc.y = a.y + b.y + c.y + d.y;
    Mt[(size_t)bid*64 + pq] = acc;
  }
}

// ---------------- out2[n,k,p,q] = sum_i Mt[n,i,k,p,q] res[i,k,p,q] ----------
__global__ __launch_bounds__(256) void k_out2(const float2* __restrict__ Mt,
    const float2* __restrict__ res, float2* __restrict__ out2) {
  int gid = blockIdx.x*256 + threadIdx.x;   // [0, 8192)
  int pq = gid & 63, k = (gid >> 6) & 15, n = gid >> 10;
  float2 acc = make_float2(0.f, 0.f);
  for (int i = 0; i < 16; ++i)
    cacc(acc, Mt[((size_t)((n*16+i)*16 + k))*64 + pq], res[((size_t)(i*16+k))*64 + pq]);
  out2[((size_t)(n*16+k))*64 + pq] = acc;
}

// ---- fused out1 + row-iFFT: block = (o, k-pair), double-buffered alpha -----
__global__ __launch_bounds__(256) void k_out1g(const float2* __restrict__ alphaR,
    const float2* __restrict__ Tt, const float2* __restrict__ A2L,
    float2* __restrict__ out1) {
  __shared__ float2 tl[2][128];       // T[i,q] at (2*kh+kk, o)
  __shared__ float sre[4][256], sim[4][256];
  int d = blockIdx.x;                 // [0, 2048)
  int xcd = d & 7, idx = d >> 3;      // idx [0, 256)
  int o  = xcd*32 + (idx >> 3);
  int kh = idx & 7;                   // k pair: 2*kh, 2*kh+1
  int tid = threadIdx.x, x = tid;
  int lane = tid & 63, rowi = tid >> 6;
  {
    int kk = tid >> 7, rem = tid & 127;
    int i = rem >> 3, q = rem & 7;
    tl[kk][rem] = Tt[((size_t)((i*16 + 2*kh + kk)*8 + q))*256 + o];
  }
  float2 tw[8];
  make_tw(+1.0f, lane, tw);
  __syncthreads();
  float2 g0[16], g1[16];
  #pragma unroll
  for (int i = 0; i < 16; ++i) {
    const float2* a2k0 = &A2L[((size_t)((i*16 + 2*kh + 0)*8))*256 + x];
    const float2* a2k1 = &A2L[((size_t)((i*16 + 2*kh + 1)*8))*256 + x];
    float2 acc0 = make_float2(0.f, 0.f), acc1 = make_float2(0.f, 0.f);
    #pragma unroll
    for (int q = 0; q < 8; ++q) {
      cacc(acc0, tl[0][i*8+q], a2k0[(size_t)q*256]);
      cacc(acc1, tl[1][i*8+q], a2k1[(size_t)q*256]);
    }
    g0[i] = acc0; g1[i] = acc1;
  }
  const float2* arow = alphaR + (size_t)o*128*256 + x;
  float2 arA[16], arB[16];
  #pragma unroll
  for (int i = 0; i < 16; ++i) arA[i] = arow[(size_t)(0*16 + i)*256];
  #pragma unroll
  for (int i = 0; i < 16; ++i) arB[i] = arow[(size_t)(1*16 + i)*256];
  for (int bp = 0; bp < 4; ++bp) {
    float2 acc0 = make_float2(0.f,0.f), acc1 = acc0, acc2 = acc0, acc3 = acc0;
    #pragma unroll
    for (int i = 0; i < 16; ++i) {
      cacc(acc0, arA[i], g0[i]);
      cacc(acc1, arA[i], g1[i]);
      cacc(acc2, arB[i], g0[i]);
      cacc(acc3, arB[i], g1[i]);
    }
    sre[0][x] = acc0.x; sim[0][x] = acc0.y;
    sre[1][x] = acc1.x; sim[1][x] = acc1.y;
    sre[2][x] = acc2.x; sim[2][x] = acc2.y;
    sre[3][x] = acc3.x; sim[3][x] = acc3.y;
    __syncthreads();
    if (bp < 3) {
      int b0 = (bp+1)*2, b1 = b0 + 1;
      #pragma unroll
      for (int i = 0; i < 16; ++i) arA[i] = arow[(size_t)(b0*16 + i)*256];
      #pragma unroll
      for (int i = 0; i < 16; ++i) arB[i] = arow[(size_t)(b1*16 + i)*256];
    }
    float2 v0 = make_float2(sre[rowi][lane],     sim[rowi][lane]);
    float2 v1 = make_float2(sre[rowi][64+lane],  sim[rowi][64+lane]);
    float2 v2 = make_float2(sre[rowi][128+lane], sim[rowi][128+lane]);
    float2 v3 = make_float2(sre[rowi][192+lane], sim[rowi][192+lane]);
    ifft256_reg(v0, v1, v2, v3, lane, tw);
    int img = (bp*2 + (rowi >> 1))*16 + 2*kh + (rowi & 1);
    float2* op = out1 + ((size_t)img*256 + o)*256;
    nts2(&op[lane], v0); nts2(&op[64+lane], v1);
    nts2(&op[128+lane], v2); nts2(&op[192+lane], v3);
    __syncthreads();
  }
}

// ---- x1pre += Re(sum_{j,q} U E2)/65536, U computed on the fly --------------
__global__ __launch_bounds__(256) void k_x2t(const float2* __restrict__ out2,
    const float2* __restrict__ E1, const float2* __restrict__ E2,
    float* __restrict__ x1pre) {
  int bid = blockIdx.x;               // (n*16+kk)*32 + zb
  int zb = bid & 31, nk = bid >> 5;
  int kk = nk & 15, n = nk >> 4;
  int x = threadIdx.x;
  __shared__ float2 o2[1024];         // [j][p][q]
  __shared__ float2 e1l[1024];        // [j][p][zz]
  __shared__ float2 ul[1024];         // [j][q][zz]
  for (int e = 0; e < 4; ++e) {
    int lin = threadIdx.x + 256*e;
    int j = lin >> 6, pq = lin & 63;
    o2[lin] = out2[((size_t)(n*16 + j))*64 + pq];
  }
  for (int e = 0; e < 4; ++e) {
    int lin = threadIdx.x + 256*e;
    int j = lin >> 6, p = (lin >> 3) & 7, zz = lin & 7;
    e1l[lin] = E1[(((size_t)(j*16 + kk))*8 + p)*256 + zb*8 + zz];
  }
  __syncthreads();
  for (int e = 0; e < 4; ++e) {
    int lin = threadIdx.x + 256*e;
    int j = lin >> 6, q = (lin >> 3) & 7, zz = lin & 7;
    float2 acc = make_float2(0.f, 0.f);
    #pragma unroll
    for (int p = 0; p < 8; ++p) cacc(acc, o2[j*64 + p*8 + q], e1l[j*64 + p*8 + zz]);
    ul[lin] = acc;
  }
  __syncthreads();
  float acc[8] = {0.f,0.f,0.f,0.f,0.f,0.f,0.f,0.f};
  const float2* e2b = E2 + (size_t)kk*2048 + x;
  float2 nxt = e2b[0];
  for (int jq = 0; jq < 128; ++jq) {
    float2 e2 = nxt;
    int njq = jq + 1;
    if (njq < 128) {
      int nj = njq >> 3, nq = njq & 7;
      nxt = e2b[(size_t)nj*32768 + (size_t)nq*256];
    }
    const float4* up4 = reinterpret_cast<const float4*>(&ul[jq*8]);
    float4 u01 = up4[0], u23 = up4[1], u45 = up4[2], u67 = up4[3];
    acc[0] = fmaf(u01.x, e2.x, fmaf(-u01.y, e2.y, acc[0]));
    acc[1] = fmaf(u01.z, e2.x, fmaf(-u01.w, e2.y, acc[1]));
    acc[2] = fmaf(u23.x, e2.x, fmaf(-u23.y, e2.y, acc[2]));
    acc[3] = fmaf(u23.z, e2.x, fmaf(-u23.w, e2.y, acc[3]));
    acc[4] = fmaf(u45.x, e2.x, fmaf(-u45.y, e2.y, acc[4]));
    acc[5] = fmaf(u45.z, e2.x, fmaf(-u45.w, e2.y, acc[5]));
    acc[6] = fmaf(u67.x, e2.x, fmaf(-u67.y, e2.y, acc[6]));
    acc[7] = fmaf(u67.z, e2.x, fmaf(-u67.w, e2.y, acc[7]));
  }
  const float sc = 1.0f/65536.0f;
  #pragma unroll
  for (int zz = 0; zz < 8; ++zz) {
    size_t idx = (((size_t)nk)*256 + zb*8 + zz)*256 + x;
    x1pre[idx] += acc[zz]*sc;
  }
}

// ---------------- final: inorm(x1pre) + w0conv(v) -> fc1 -> sin -> fc2 ------
__global__ __launch_bounds__(256) void k_final(const float* __restrict__ x,
    const float* __restrict__ x1pre, const float2* __restrict__ stats2,
    const float* __restrict__ fc0w, const float* __restrict__ fc0b,
    const float* __restrict__ w0w, const float* __restrict__ w0b,
    const float* __restrict__ fc1w, const float* __restrict__ fc1b,
    const float* __restrict__ fc2w, const float* __restrict__ fc2b,
    float* __restrict__ out) {
  __shared__ float s_fc1w[2048], s_fc1b[128], s_fc2w[384], s_w0w[256], s_w0b[16], s_fc2b[3];
  int tid = threadIdx.x;
  for (int e = 0; e < 8; ++e) s_fc1w[tid + 256*e] = fc1w[tid + 256*e];
  if (tid < 128) s_fc1b[tid] = fc1b[tid];
  for (int e = 0; e < 2; ++e) { int q = tid + 256*e; if (q < 384) s_fc2w[q] = fc2w[q]; }
  s_w0w[tid] = w0w[tid];
  if (tid < 16) s_w0b[tid] = w0b[tid];
  if (tid < 3)  s_fc2b[tid] = fc2b[tid];
  __syncthreads();

  int bid = blockIdx.x;               // b*256 + h
  int hh = bid & 255, b = bid >> 8;
  int ww = tid;
  size_t pix = (size_t)hh*256 + ww;
  float xc0 = x[((size_t)b*3 + 0)*NPIX + pix];
  float xc1 = x[((size_t)b*3 + 1)*NPIX + pix];
  float xc2 = x[((size_t)b*3 + 2)*NPIX + pix];
  float gx = hh*(1.0f/255.0f), gy = ww*(1.0f/255.0f);
  float v[16], x1n[16], uo[16];
  #pragma unroll
  for (int k = 0; k < 16; ++k)
    v[k] = fc0b[k] + xc0*fc0w[k] + xc1*fc0w[16+k] + xc2*fc0w[32+k] + gx*fc0w[48+k] + gy*fc0w[64+k];
  #pragma unroll
  for (int k = 0; k < 16; ++k) {
    float2 st = stats2[b*16 + k];
    float xv = x1pre[((size_t)(b*16 + k))*NPIX + pix];
    x1n[k] = (xv - st.x)*st.y;
  }
  #pragma unroll
  for (int o = 0; o < 16; ++o) {
    float acc = s_w0b[o];
    #pragma unroll
    for (int k = 0; k < 16; ++k) acc = fmaf(v[k], s_w0w[o*16+k], acc);
    uo[o] = acc + x1n[o];
  }
  float o0 = 0.f, o1 = 0.f, o2 = 0.f;
  for (int jj = 0; jj < 128; ++jj) {
    float t = s_fc1b[jj];
    #pragma unroll
    for (int k = 0; k < 16; ++k) t = fmaf(uo[k], s_fc1w[k*128 + jj], t);
    float s = __sinf(t);
    o0 = fmaf(s, s_fc2w[jj*3+0], o0);
    o1 = fmaf(s, s_fc2w[jj*3+1], o1);
    o2 = fmaf(s, s_fc2w[jj*3+2], o2);
  }
  out[((size_t)b*3 + 0)*NPIX + pix] = o0 + s_fc2b[0];
  out[((size_t)b*3 + 1)*NPIX + pix] = o1 + s_fc2b[1];
  out[((size_t)b*3 + 2)*NPIX + pix] = o2 + s_fc2b[2];
}

// ---------------------------------------------------------------------------
extern "C" void kernel_launch(void* const* d_in, const int* in_sizes, int n_in,
                              void* d_out, int out_size, void* d_ws, size_t ws_size,
                              hipStream_t stream) {
  const float*  x    = (const float*)d_in[0];
  const float*  fc0w = (const float*)d_in[1];
  const float*  fc0b = (const float*)d_in[2];
  const float2* p1   = (const float2*)d_in[3];
  const float2* p2   = (const float2*)d_in[4];
  const float2* res  = (const float2*)d_in[5];
  const float*  w0w  = (const float*)d_in[6];
  const float*  w0b  = (const float*)d_in[7];
  const float*  fc1w = (const float*)d_in[8];
  const float*  fc1b = (const float*)d_in[9];
  const float*  fc2w = (const float*)d_in[10];
  const float*  fc2b = (const float*)d_in[11];
  const float*  txv  = (const float*)d_in[12];
  const float*  tyv  = (const float*)d_in[13];
  float* out = (float*)d_out;

  // workspace layout (bytes); NEED == proven-safe 252,774,400
  const size_t OFF_A1   = 0;            // 4 MiB
  const size_t OFF_A2T  = 4194304;      // 4 MiB
  const size_t OFF_E1   = 8388608;      // 4 MiB
  const size_t OFF_E2   = 12582912;     // 4 MiB
  const size_t OFF_ST1  = 16777216;
  const size_t OFF_ST2  = 16778240;
  const size_t OFF_OUT2 = 16779264;     // 64 KiB
  const size_t OFF_MT   = 16844800;     // 1 MiB
  const size_t OFF_S    = 17893376;     // 32 MiB  (stats partials early; S)
  const size_t OFF_X1   = 51447808;     // 32 MiB  (Tt 4MiB early; X1 real later)
  const size_t OFF_A    = 85002240;     // 64 MiB  (row-fft out; later out1 row-ifft'd)
  const size_t OFF_B    = 152111104;    // 64 MiB  (alphaR o-major)
  const size_t OFF_G    = 219219968;    // 32 MiB  (A2L 4MiB + BH 4MiB + BL 4MiB)
  const size_t NEED     = 252774400;
  if (ws_size < NEED) return;
  char* ws = (char*)d_ws;
  float2* A1  = (float2*)(ws + OFF_A1);
  float2* A2T = (float2*)(ws + OFF_A2T);
  float2* E1  = (float2*)(ws + OFF_E1);
  float2* E2  = (float2*)(ws + OFF_E2);
  float2* st1 = (float2*)(ws + OFF_ST1);
  float2* st2 = (float2*)(ws + OFF_ST2);
  float2* o2b = (float2*)(ws + OFF_OUT2);
  float2* Mt  = (float2*)(ws + OFF_MT);
  float2* Sb  = (float2*)(ws + OFF_S);
  float2* Tt  = (float2*)(ws + OFF_X1);   // dead before X1 is written
  float*  X1  = (float*)(ws + OFF_X1);
  float2* Ab  = (float2*)(ws + OFF_A);
  float2* Bb  = (float2*)(ws + OFF_B);
  float2* A2L = (float2*)(ws + OFF_G);
  u16*    BH  = (u16*)(ws + OFF_G + 4194304);
  u16*    BL  = (u16*)(ws + OFF_G + 8388608);

  k_setup  <<<2048, 256, 0, stream>>>(p1, p2, txv, tyv, A1, A2T, A2L, E1, E2);
  k_B      <<<128, 256, 0, stream>>>(A2T, BH, BL);
  k_T      <<<256, 256, 0, stream>>>(res, A1, Tt);
  // stats of v: two-stage; partials in Sb (dead region)
  k_stats_v_part<<<1024, 256, 0, stream>>>(x, fc0w, fc0b, Sb);
  k_stats_fin   <<<1, 256, 0, stream>>>(Sb, st1, 128);
  // forward fft2: in-register DIF rows (brev-x out) into Ab, columns -> alphaR (Bb)
  k_fft_v  <<<8192, 256, 0, stream>>>(x, fc0w, fc0b, st1, Ab);
  k_fft_colR<<<2048, 256, 0, stream>>>(Ab, Bb);                 // Bb = alphaR [o][bi][xp]
  // pole-residue spectral sums: MFMA S-GEMM
  k_Smm    <<<512, 256, 0, stream>>>(Bb, BH, BL, (float*)Sb);
  k_Mt     <<<2048, 256, 0, stream>>>(Sb, A1, Mt);
  k_out2   <<<32, 256, 0, stream>>>(Mt, res, o2b);
  // fused out1 + in-register row-iFFT, per (o, k-pair) block, dbuf alpha
  k_out1g  <<<2048, 256, 0, stream>>>(Bb, Tt, A2L, Ab);         // Ab = row-ifft'd out1
  // inverse column FFT, real output
  k_ifft_col_real<<<2048, 256, 0, stream>>>(Ab, X1, 1.0f/65536.0f); // X1 [img][h][w]
  // transient part added into x1pre (U folded in)
  k_x2t    <<<4096, 256, 0, stream>>>(o2b, E1, E2, X1);
  // second instance norm (two-stage) + heads
  k_stats_p_part<<<1024, 256, 0, stream>>>(X1, Sb);
  k_stats_fin   <<<1, 256, 0, stream>>>(Sb, st2, 128);
  k_final  <<<2048, 256, 0, stream>>>(x, X1, st2, fc0w, fc0b,
                                      w0w, w0b, fc1w, fc1b, fc2w, fc2b, out);
}

// Round 16
// 501.984 us; speedup vs baseline: 1.0357x; 1.0357x over previous
//
#include <hip/hip_runtime.h>
#include <cstddef>

#define NPIX 65536
#define PI_F 3.14159265358979323846f

typedef float v4f __attribute__((ext_vector_type(4)));
typedef short v8s __attribute__((ext_vector_type(8)));
typedef unsigned short u16;

__device__ __forceinline__ void cacc(float2& acc, float2 a, float2 b) {
  acc.x = fmaf(a.x, b.x, fmaf(-a.y, b.y, acc.x));
  acc.y = fmaf(a.x, b.y, fmaf(a.y, b.x, acc.y));
}
__device__ __forceinline__ float2 cmulf(float2 a, float2 b) {
  return make_float2(a.x*b.x - a.y*b.y, a.x*b.y + a.y*b.x);
}
__device__ __forceinline__ float2 add2(float2 a, float2 b) { return make_float2(a.x+b.x, a.y+b.y); }
__device__ __forceinline__ float2 sub2(float2 a, float2 b) { return make_float2(a.x-b.x, a.y-b.y); }
__device__ __forceinline__ float2 shflc(float2 v, int mask) {
  return make_float2(__shfl_xor(v.x, mask), __shfl_xor(v.y, mask));
}
__device__ __forceinline__ void nts2(float2* p, float2 v) {
  __builtin_nontemporal_store(*reinterpret_cast<const double*>(&v),
                              reinterpret_cast<double*>(p));
}
__device__ __forceinline__ void nts1(float* p, float v) {
  __builtin_nontemporal_store(v, p);
}
__device__ __forceinline__ void bf16split(float v, u16& h, u16& l) {
  unsigned bits = __float_as_uint(v);
  h = (u16)(bits >> 16);
  float r = v - __uint_as_float((unsigned)h << 16);
  l = (u16)(__float_as_uint(r) >> 16);
}
__device__ __forceinline__ void make_tw(float sgn, int l, float2* tw) {
  const float c = sgn * (2.0f*PI_F/256.0f);
  int idxs[8] = { l, 64+l, 2*l, (l&31)<<2, (l&15)<<3, (l&7)<<4, (l&3)<<5, (l&1)<<6 };
  #pragma unroll
  for (int r = 0; r < 8; ++r) { float sn, cs; __sincosf(c*idxs[r], &sn, &cs); tw[r] = make_float2(cs, sn); }
}
__device__ __forceinline__ void fwd_stage(float2& vv, int lane, int H, float2 tws, bool unit) {
  float2 p = shflc(vv, H);
  bool up = (lane & H) != 0;
  float2 lo = add2(vv, p);
  float2 df = sub2(p, vv);
  float2 hi = unit ? df : cmulf(df, tws);
  vv = up ? hi : lo;
}
__device__ __forceinline__ void inv_stage(float2& vv, int lane, int H, float2 tws, bool unit) {
  float2 p = shflc(vv, H);
  bool up = (lane & H) != 0;
  float2 bv = up ? vv : p;
  float2 av = up ? p : vv;
  float2 t = unit ? bv : cmulf(bv, tws);
  vv = up ? sub2(av, t) : add2(av, t);
}
__device__ __forceinline__ void ifft256_reg(float2& v0, float2& v1, float2& v2,
    float2& v3, int lane, const float2* tw) {
  inv_stage(v0, lane, 1, tw[0], true ); inv_stage(v1, lane, 1, tw[0], true );
  inv_stage(v2, lane, 1, tw[0], true ); inv_stage(v3, lane, 1, tw[0], true );
  inv_stage(v0, lane, 2, tw[7], false); inv_stage(v1, lane, 2, tw[7], false);
  inv_stage(v2, lane, 2, tw[7], false); inv_stage(v3, lane, 2, tw[7], false);
  inv_stage(v0, lane, 4, tw[6], false); inv_stage(v1, lane, 4, tw[6], false);
  inv_stage(v2, lane, 4, tw[6], false); inv_stage(v3, lane, 4, tw[6], false);
  inv_stage(v0, lane, 8, tw[5], false); inv_stage(v1, lane, 8, tw[5], false);
  inv_stage(v2, lane, 8, tw[5], false); inv_stage(v3, lane, 8, tw[5], false);
  inv_stage(v0, lane, 16, tw[4], false); inv_stage(v1, lane, 16, tw[4], false);
  inv_stage(v2, lane, 16, tw[4], false); inv_stage(v3, lane, 16, tw[4], false);
  inv_stage(v0, lane, 32, tw[3], false); inv_stage(v1, lane, 32, tw[3], false);
  inv_stage(v2, lane, 32, tw[3], false); inv_stage(v3, lane, 32, tw[3], false);
  { float2 t01 = cmulf(v1, tw[2]); float2 n0 = add2(v0, t01), n1 = sub2(v0, t01);
    float2 t23 = cmulf(v3, tw[2]); float2 n2 = add2(v2, t23), n3 = sub2(v2, t23);
    v0 = n0; v1 = n1; v2 = n2; v3 = n3; }
  { float2 t02 = cmulf(v2, tw[0]); float2 n0 = add2(v0, t02), n2 = sub2(v0, t02);
    float2 t13 = cmulf(v3, tw[1]); float2 n1 = add2(v1, t13), n3 = sub2(v1, t13);
    v0 = n0; v2 = n2; v1 = n1; v3 = n3; }
}

// ---------------- setup: A1, A2T, A2L (brev-x domain), E1, E2 ---------------
__global__ __launch_bounds__(256) void k_setup(const float2* __restrict__ p1,
    const float2* __restrict__ p2, const float* __restrict__ txv,
    const float* __restrict__ tyv, float2* __restrict__ A1,
    float2* __restrict__ A2T, float2* __restrict__ A2L,
    float2* __restrict__ E1, float2* __restrict__ E2) {
  int gid = blockIdx.x*256 + threadIdx.x;          // [0, 524288)
  int o = gid & 255, p = (gid>>8)&7, k = (gid>>11)&15, i = gid>>15;
  float ko = (o < 128) ? (float)o : (float)(o - 256);
  float dty = tyv[1] - tyv[0];
  float dtx = txv[1] - txv[0];
  const float TWO_PI = 6.283185307179586f;
  {
    float lam = TWO_PI * ko / (256.0f * dty);
    float2 pv = p1[(i*16+k)*8 + p];
    float xr = -pv.x, yi = lam - pv.y;
    float D = xr*xr + yi*yi;
    A1[((size_t)((i*16+k)*8 + p))*256 + o] = make_float2(xr/D, -yi/D);
    float tv = tyv[o];
    float m = expf(pv.x*tv);
    E1[((size_t)((i*16+k)*8 + p))*256 + o] = make_float2(m*cosf(pv.y*tv), m*sinf(pv.y*tv));
  }
  {
    int fo = __brev((unsigned)o) >> 24;
    float ko2 = (fo < 128) ? (float)fo : (float)(fo - 256);
    float lam = TWO_PI * ko2 / (256.0f * dtx);
    float2 pv = p2[(i*16+k)*8 + p];
    float xr = -pv.x, yi = lam - pv.y;
    float D = xr*xr + yi*yi;
    float2 val = make_float2(xr/D, -yi/D);
    A2T[((size_t)i*256 + o)*128 + k*8 + p] = val;
    A2L[((size_t)((i*16+k)*8 + p))*256 + o] = val;
    float tv = txv[o];
    float m = expf(pv.x*tv);
    E2[((size_t)((i*16+k)*8 + p))*256 + o] = make_float2(m*cosf(pv.y*tv), m*sinf(pv.y*tv));
  }
}

// ---- build BT_big (bf16 hi/lo) from A2T:  BT[i][n2][k2] --------------------
__global__ __launch_bounds__(256) void k_B(const float2* __restrict__ A2T,
    u16* __restrict__ BH, u16* __restrict__ BL) {
  int bid = blockIdx.x;               // i*8 + g
  int i = bid >> 3, g = bid & 7;
  int tid = threadIdx.x;
  int n2 = g*32 + (tid >> 3);
  int kq = n2 >> 1, par = n2 & 1;
  int x0 = (tid & 7) * 32;
  size_t outb = ((size_t)i*256 + n2)*512;
  for (int xx = 0; xx < 32; ++xx) {
    int x = x0 + xx;
    float2 a2 = A2T[((size_t)i*256 + x)*128 + kq];
    float v0 = par ? a2.y : a2.x;
    float v1 = par ? a2.x : -a2.y;
    u16 h0, l0, h1, l1;
    bf16split(v0, h0, l0);
    bf16split(v1, h1, l1);
    BH[outb + 2*x]     = h0;  BL[outb + 2*x]     = l0;
    BH[outb + 2*x + 1] = h1;  BL[outb + 2*x + 1] = l1;
  }
}

// ---- split E2 -> EH/EL [kk][x][k2], k2 = 2jq (+Re) / 2jq+1 (-Im) -----------
__global__ __launch_bounds__(256) void k_E2s(const float2* __restrict__ E2,
    unsigned* __restrict__ EH32, unsigned* __restrict__ EL32) {
  int kk = blockIdx.x;
  int x = threadIdx.x;
  for (int jq = 0; jq < 128; ++jq) {
    int j = jq >> 3, q = jq & 7;
    float2 e2 = E2[(((size_t)(j*16 + kk))*8 + q)*256 + x];
    u16 h0,l0,h1,l1;
    bf16split(e2.x, h0, l0);
    bf16split(-e2.y, h1, l1);
    size_t idx = ((size_t)kk*256 + x)*128 + jq;
    EH32[idx] = (unsigned)h0 | ((unsigned)h1 << 16);
    EL32[idx] = (unsigned)l0 | ((unsigned)l1 << 16);
  }
}

// ---------------- T[ik][q][o] = sum_p res[ik][p][q] A1[ik][p][o] ------------
__global__ __launch_bounds__(256) void k_T(const float2* __restrict__ res,
    const float2* __restrict__ A1, float2* __restrict__ Tt) {
  int ik = blockIdx.x, tid = threadIdx.x;
  __shared__ float2 rbuf[64];
  __shared__ float2 a1[8][256];
  if (tid < 64) rbuf[tid] = res[(size_t)ik*64 + tid];
  for (int e = 0; e < 8; ++e) {
    int lin = tid + 256*e;
    int p = lin >> 8, o = lin & 255;
    a1[p][o] = A1[((size_t)ik*8 + p)*256 + o];
  }
  __syncthreads();
  int o = tid;
  #pragma unroll
  for (int q = 0; q < 8; ++q) {
    float2 acc = make_float2(0.f, 0.f);
    #pragma unroll
    for (int p = 0; p < 8; ++p) cacc(acc, rbuf[p*8+q], a1[p][o]);
    Tt[((size_t)ik*8 + q)*256 + o] = acc;
  }
}

// ---- stats partials of v (recomputed from x) -------------------------------
__global__ __launch_bounds__(256) void k_stats_v_part(const float* __restrict__ x,
    const float* __restrict__ fc0w, const float* __restrict__ fc0b,
    float2* __restrict__ part) {
  int bid = blockIdx.x;               // img*8 + seg
  int seg = bid & 7, img = bid >> 3;
  int k = img & 15, b = img >> 4;
  int tid = threadIdx.x;
  float w0 = fc0w[k], w1 = fc0w[16+k], w2 = fc0w[32+k], w3 = fc0w[48+k], w4 = fc0w[64+k];
  float base = fc0b[k] + (tid*(1.0f/255.0f))*w4;
  const float* xb = x + (size_t)b*3*NPIX + (size_t)seg*8192;
  float s = 0.f, s2 = 0.f;
  for (int it = 0; it < 32; ++it) {
    int row = seg*32 + it;
    int p = it*256 + tid;
    float val = base + (row*(1.0f/255.0f))*w3 + xb[p]*w0 + xb[NPIX+p]*w1 + xb[2*NPIX+p]*w2;
    s += val; s2 += val*val;
  }
  __shared__ float rs[256], rq[256];
  rs[tid] = s; rq[tid] = s2;
  __syncthreads();
  for (int off = 128; off > 0; off >>= 1) {
    if (tid < off) { rs[tid] += rs[tid+off]; rq[tid] += rq[tid+off]; }
    __syncthreads();
  }
  if (tid == 0) part[bid] = make_float2(rs[0], rq[0]);
}

// ---- stats partials of a real plane buffer ---------------------------------
__global__ __launch_bounds__(256) void k_stats_p_part(const float* __restrict__ v,
    float2* __restrict__ part) {
  int bid = blockIdx.x;               // img*8 + seg
  int seg = bid & 7, img = bid >> 3;
  int tid = threadIdx.x;
  const float* p = v + (size_t)img*NPIX + (size_t)seg*8192;
  float s = 0.f, s2 = 0.f;
  for (int it = 0; it < 32; ++it) { float a = p[it*256 + tid]; s += a; s2 += a*a; }
  __shared__ float rs[256], rq[256];
  rs[tid] = s; rq[tid] = s2;
  __syncthreads();
  for (int off = 128; off > 0; off >>= 1) {
    if (tid < off) { rs[tid] += rs[tid+off]; rq[tid] += rq[tid+off]; }
    __syncthreads();
  }
  if (tid == 0) part[bid] = make_float2(rs[0], rq[0]);
}

// ---- combine 8 partials per img -> stats -----------------------------------
__global__ __launch_bounds__(256) void k_stats_fin(const float2* __restrict__ part,
    float2* __restrict__ stats, int nimg) {
  int img = blockIdx.x*256 + threadIdx.x;
  if (img >= nimg) return;
  float s = 0.f, s2 = 0.f;
  #pragma unroll
  for (int e = 0; e < 8; ++e) { float2 v = part[img*8 + e]; s += v.x; s2 += v.y; }
  float mean = s * (1.0f/65536.0f);
  float var  = s2 * (1.0f/65536.0f) - mean*mean;
  stats[img] = make_float2(mean, rsqrtf(var + 1e-5f));
}

// ---- row FFT of normalized v, in-register DIF (brev-x out) -----------------
__global__ __launch_bounds__(256) void k_fft_v(const float* __restrict__ x,
    const float* __restrict__ fc0w, const float* __restrict__ fc0b,
    const float2* __restrict__ stats, float2* __restrict__ out) {
  int tid = threadIdx.x, lane = tid & 63, rowi = tid >> 6;
  int bid = blockIdx.x;
  int img = bid >> 6;
  int h   = (bid & 63)*4 + rowi;
  int k = img & 15, b = img >> 4;
  float2 st = stats[img];
  float w0 = fc0w[k], w1 = fc0w[16+k], w2 = fc0w[32+k], w3 = fc0w[48+k], w4 = fc0w[64+k];
  float bb = fc0b[k] + (h*(1.0f/255.0f))*w3;
  const float* xb = x + (size_t)b*3*NPIX + (size_t)h*256;
  float2 tw[8];
  make_tw(-1.0f, lane, tw);
  float2 v0, v1, v2, v3;
  {
    #pragma unroll
    for (int e = 0; e < 4; ++e) {
      int j = e*64 + lane;
      float val = bb + (j*(1.0f/255.0f))*w4 + xb[j]*w0 + xb[NPIX+j]*w1 + xb[2*NPIX+j]*w2;
      val = (val - st.x)*st.y;
      float2 c = make_float2(val, 0.f);
      if (e == 0) v0 = c; else if (e == 1) v1 = c; else if (e == 2) v2 = c; else v3 = c;
    }
  }
  { float2 n0 = add2(v0, v2), n2 = cmulf(sub2(v0, v2), tw[0]);
    float2 n1 = add2(v1, v3), n3 = cmulf(sub2(v1, v3), tw[1]);
    v0 = n0; v1 = n1; v2 = n2; v3 = n3; }
  { float2 n0 = add2(v0, v1), n1 = cmulf(sub2(v0, v1), tw[2]);
    float2 n2 = add2(v2, v3), n3 = cmulf(sub2(v2, v3), tw[2]);
    v0 = n0; v1 = n1; v2 = n2; v3 = n3; }
  fwd_stage(v0, lane, 32, tw[3], false); fwd_stage(v1, lane, 32, tw[3], false);
  fwd_stage(v2, lane, 32, tw[3], false); fwd_stage(v3, lane, 32, tw[3], false);
  fwd_stage(v0, lane, 16, tw[4], false); fwd_stage(v1, lane, 16, tw[4], false);
  fwd_stage(v2, lane, 16, tw[4], false); fwd_stage(v3, lane, 16, tw[4], false);
  fwd_stage(v0, lane,  8, tw[5], false); fwd_stage(v1, lane,  8, tw[5], false);
  fwd_stage(v2, lane,  8, tw[5], false); fwd_stage(v3, lane,  8, tw[5], false);
  fwd_stage(v0, lane,  4, tw[6], false); fwd_stage(v1, lane,  4, tw[6], false);
  fwd_stage(v2, lane,  4, tw[6], false); fwd_stage(v3, lane,  4, tw[6], false);
  fwd_stage(v0, lane,  2, tw[7], false); fwd_stage(v1, lane,  2, tw[7], false);
  fwd_stage(v2, lane,  2, tw[7], false); fwd_stage(v3, lane,  2, tw[7], false);
  fwd_stage(v0, lane,  1, tw[0], true ); fwd_stage(v1, lane,  1, tw[0], true );
  fwd_stage(v2, lane,  1, tw[0], true ); fwd_stage(v3, lane,  1, tw[0], true );
  float2* op = out + ((size_t)img*256 + h)*256;
  nts2(&op[lane], v0); nts2(&op[64+lane], v1);
  nts2(&op[128+lane], v2); nts2(&op[192+lane], v3);
}

// ---- forward column FFT, writes o-major alphaR[o][img][x] ------------------
__global__ __launch_bounds__(256) void k_fft_colR(const float2* __restrict__ in,
    float2* __restrict__ outp) {
  __shared__ float tr[256][17], tim[256][17];
  __shared__ float twr[128], twi[128];
  int tid = threadIdx.x;
  int c = tid & 15, g = tid >> 4;
  int img = blockIdx.x >> 4;
  int c0  = (blockIdx.x & 15) * 16;
  if (tid < 128) {
    float ang = (PI_F/128.0f)*tid;
    twr[tid] = cosf(ang); twi[tid] = -sinf(ang);
  }
  const float2* base = in + (size_t)img*NPIX + c0;
  #pragma unroll
  for (int it = 0; it < 16; ++it) {
    int row = it*16 + g;
    float2 v = base[(size_t)row*256 + c];
    int br = __brev((unsigned)row) >> 24;
    tr[br][c] = v.x; tim[br][c] = v.y;
  }
  __syncthreads();
  int lane = tid & 63, w = tid >> 6;
  int cw = w*4 + (lane >> 4);
  int gw = lane & 15;
  for (int s = 0; s < 8; ++s) {
    __builtin_amdgcn_wave_barrier();
    int half = 1 << s;
    #pragma unroll
    for (int r = 0; r < 8; ++r) {
      int m  = gw + 16*r;
      int t  = m & (half - 1);
      int grp = m >> s;
      int i0 = (grp << (s+1)) + t;
      int i1 = i0 + half;
      int twx = t << (7 - s);
      float wr = twr[twx], wi = twi[twx];
      float br = tr[i1][cw], bi = tim[i1][cw];
      float vr = br*wr - bi*wi, vi = br*wi + bi*wr;
      float ar = tr[i0][cw], ai = tim[i0][cw];
      tr[i0][cw] = ar + vr; tim[i0][cw] = ai + vi;
      tr[i1][cw] = ar - vr; tim[i1][cw] = ai - vi;
    }
  }
  __syncthreads();
  #pragma unroll
  for (int it = 0; it < 16; ++it) {
    int row = it*16 + g;
    float2 vv = make_float2(tr[row][c], tim[row][c]);
    nts2(&outp[((size_t)row*128 + img)*256 + c0 + c], vv);
  }
}

// ---------------- column inverse FFT, write real part to out ---------------
__global__ __launch_bounds__(256) void k_ifft_col_real(const float2* __restrict__ in,
    float* __restrict__ outp, float scale) {
  __shared__ float tr[256][17], tim[256][17];
  __shared__ float twr[128], twi[128];
  int tid = threadIdx.x;
  int c = tid & 15, g = tid >> 4;
  int img = blockIdx.x >> 4;
  int c0  = (blockIdx.x & 15) * 16;
  if (tid < 128) {
    float ang = (PI_F/128.0f)*tid;
    twr[tid] = cosf(ang); twi[tid] = sinf(ang);
  }
  const float2* base = in + (size_t)img*NPIX + c0;
  #pragma unroll
  for (int it = 0; it < 16; ++it) {
    int row = it*16 + g;
    float2 v = base[(size_t)row*256 + c];
    int br = __brev((unsigned)row) >> 24;
    tr[br][c] = v.x; tim[br][c] = v.y;
  }
  __syncthreads();
  int lane = tid & 63, w = tid >> 6;
  int cw = w*4 + (lane >> 4);
  int gw = lane & 15;
  for (int s = 0; s < 8; ++s) {
    __builtin_amdgcn_wave_barrier();
    int half = 1 << s;
    #pragma unroll
    for (int r = 0; r < 8; ++r) {
      int m  = gw + 16*r;
      int t  = m & (half - 1);
      int grp = m >> s;
      int i0 = (grp << (s+1)) + t;
      int i1 = i0 + half;
      int twx = t << (7 - s);
      float wr = twr[twx], wi = twi[twx];
      float br = tr[i1][cw], bi = tim[i1][cw];
      float vr = br*wr - bi*wi, vi = br*wi + bi*wr;
      float ar = tr[i0][cw], ai = tim[i0][cw];
      tr[i0][cw] = ar + vr; tim[i0][cw] = ai + vi;
      tr[i1][cw] = ar - vr; tim[i1][cw] = ai - vi;
    }
  }
  __syncthreads();
  float* ob = outp + (size_t)img*NPIX + c0;
  #pragma unroll
  for (int it = 0; it < 16; ++it) {
    int row = it*16 + g;
    nts1(&ob[(size_t)row*256 + c], tr[row][c]*scale);
  }
}

// ---- MFMA S-GEMM: per i, S_real[2048][256] = A_real[2048][512] x B[512][256]
__global__ __launch_bounds__(256) void k_Smm(const float2* __restrict__ alphaR,
    const u16* __restrict__ BH, const u16* __restrict__ BL,
    float* __restrict__ Sf) {
  __shared__ u16 Ah[128][40], Al[128][40], Bhs[128][40], Bls[128][40];
  int bid = blockIdx.x;               // i*32 + mt*2 + nt
  int i = bid >> 5, rem = bid & 31, mt = rem >> 1, nt = rem & 1;
  int tid = threadIdx.x;
  int lane = tid & 63, wid = tid >> 6, wr = wid >> 1, wc = wid & 1;
  int r2 = tid >> 1, h2 = tid & 1;
  int m_s = mt*128 + r2;
  const float2* arow = alphaR + ((size_t)((m_s & 255)*128) + (size_t)((m_s >> 8)*16 + i))*256 + h2*8;
  const u16* bhrow = BH + ((size_t)i*256 + nt*128 + r2)*512 + h2*16;
  const u16* blrow = BL + ((size_t)i*256 + nt*128 + r2)*512 + h2*16;
  v4f acc[4][4];
  #pragma unroll
  for (int a = 0; a < 4; ++a)
    #pragma unroll
    for (int b = 0; b < 4; ++b) acc[a][b] = (v4f){0.f, 0.f, 0.f, 0.f};
  for (int kc = 0; kc < 16; ++kc) {
    const float2* ap = arow + kc*16;
    #pragma unroll
    for (int e = 0; e < 8; ++e) {
      float2 v = ap[e];
      u16 hr, lr, hi_, li_;
      bf16split(v.x, hr, lr);
      bf16split(v.y, hi_, li_);
      int c = h2*16 + 2*e;
      Ah[r2][c] = hr; Ah[r2][c+1] = hi_;
      Al[r2][c] = lr; Al[r2][c+1] = li_;
    }
    {
      const uint4* ph = (const uint4*)(bhrow + (size_t)kc*32);
      uint4 q0 = ph[0], q1 = ph[1];
      *((uint4*)&Bhs[r2][h2*16])     = q0;
      *((uint4*)&Bhs[r2][h2*16 + 8]) = q1;
      const uint4* pl = (const uint4*)(blrow + (size_t)kc*32);
      uint4 s0 = pl[0], s1 = pl[1];
      *((uint4*)&Bls[r2][h2*16])     = s0;
      *((uint4*)&Bls[r2][h2*16 + 8]) = s1;
    }
    __syncthreads();
    v8s af_h[4], af_l[4];
    int c8 = (lane >> 4) * 8;
    #pragma unroll
    for (int fi = 0; fi < 4; ++fi) {
      int row = wr*64 + fi*16 + (lane & 15);
      af_h[fi] = *(const v8s*)&Ah[row][c8];
      af_l[fi] = *(const v8s*)&Al[row][c8];
    }
    #pragma unroll
    for (int fj = 0; fj < 4; ++fj) {
      int row = wc*64 + fj*16 + (lane & 15);
      v8s bh_f = *(const v8s*)&Bhs[row][c8];
      v8s bl_f = *(const v8s*)&Bls[row][c8];
      #pragma unroll
      for (int fi = 0; fi < 4; ++fi) {
        acc[fi][fj] = __builtin_amdgcn_mfma_f32_16x16x32_bf16(af_h[fi], bh_f, acc[fi][fj], 0, 0, 0);
        acc[fi][fj] = __builtin_amdgcn_mfma_f32_16x16x32_bf16(af_l[fi], bh_f, acc[fi][fj], 0, 0, 0);
        acc[fi][fj] = __builtin_amdgcn_mfma_f32_16x16x32_bf16(af_h[fi], bl_f, acc[fi][fj], 0, 0, 0);
      }
    }
    __syncthreads();
  }
  #pragma unroll
  for (int fi = 0; fi < 4; ++fi) {
    #pragma unroll
    for (int rr = 0; rr < 4; ++rr) {
      int m = mt*128 + wr*64 + fi*16 + (lane >> 4)*4 + rr;
      int n = m >> 8, o = m & 255;
      float* srow = Sf + ((size_t)(n*16 + i)*256 + o)*256 + nt*128 + wc*64 + (lane & 15);
      #pragma unroll
      for (int fj = 0; fj < 4; ++fj)
        nts1(&srow[fj*16], acc[fi][fj][rr]);
    }
  }
}

// ---------------- Mt[n,i,k,p,q] = sum_o S[n,i,o,(k,q)] A1[i,k,p,o] ----------
__global__ __launch_bounds__(256) void k_Mt(const float2* __restrict__ S,
    const float2* __restrict__ A1, float2* __restrict__ Mt) {
  __shared__ float2 sl[8][258];
  __shared__ float2 a1l[8][258];
  __shared__ float2 part[4][64];
  int bid = blockIdx.x;               // (n*16+i)*16 + k
  int k = bid & 15, ni = bid >> 4;
  int i = ni & 15;
  int ik = i*16 + k;
  int tid = threadIdx.x;
  for (int e = 0; e < 8; ++e) {
    int lin = tid + 256*e;
    int o = lin >> 3, q = lin & 7;
    sl[q][o] = S[((size_t)ni*256 + o)*128 + k*8 + q];
  }
  for (int e = 0; e < 8; ++e) {
    int lin = tid + 256*e;
    int p = lin >> 8, o = lin & 255;
    a1l[p][o] = A1[((size_t)ik*8 + p)*256 + o];
  }
  __syncthreads();
  int oq = tid >> 6, pq = tid & 63, p = pq >> 3, q = pq & 7;
  float2 acc = make_float2(0.f, 0.f);
  int o0 = oq*64;
  for (int o = o0; o < o0 + 64; ++o) cacc(acc, sl[q][o], a1l[p][o]);
  part[oq][pq] = acc;
  __syncthreads();
  if (oq == 0) {
    float2 a = part[0][pq], b = part[1][pq], c = part[2][pq], d = part[3][pq];
    acc.x = a.x + b.x + c.x + d.x;
    acc.y = a.y + b.y + c.y + d.y;
    Mt[(size_t)bid*64 + pq] = acc;
  }
}

// ---------------- out2[n,k,p,q] = sum_i Mt[n,i,k,p,q] res[i,k,p,q] ----------
__global__ __launch_bounds__(256) void k_out2(const float2* __restrict__ Mt,
    const float2* __restrict__ res, float2* __restrict__ out2) {
  int gid = blockIdx.x*256 + threadIdx.x;
  int pq = gid & 63, k = (gid >> 6) & 15, n = gid >> 10;
  float2 acc = make_float2(0.f, 0.f);
  for (int i = 0; i < 16; ++i)
    cacc(acc, Mt[((size_t)((n*16+i)*16 + k))*64 + pq], res[((size_t)(i*16+k))*64 + pq]);
  out2[((size_t)(n*16+k))*64 + pq] = acc;
}

// ---- build U (split bf16) : U[j,q,z] = sum_p out2[n,j,p,q] E1[j,kk,p,z] ----
// A-layout for x2t GEMM: U*[batch][z][k2], k2 = 2jq (Re) / 2jq+1 (Im), packed
__global__ __launch_bounds__(256) void k_Umm(const float2* __restrict__ out2,
    const float2* __restrict__ E1, unsigned* __restrict__ UH32,
    unsigned* __restrict__ UL32) {
  __shared__ float2 o2l[1024];        // [j][p][q]
  __shared__ float2 ul[64][129];      // [z-in-chunk][jq], padded
  int batch = blockIdx.x;             // n*16 + kk
  int kk = batch & 15, n = batch >> 4;
  int tid = threadIdx.x, lane = tid & 63, w = tid >> 6;
  for (int e = 0; e < 4; ++e) {
    int lin = tid + 256*e;
    int j = lin >> 6, pq = lin & 63;
    o2l[lin] = out2[((size_t)(n*16 + j))*64 + pq];
  }
  __syncthreads();
  for (int zc = 0; zc < 4; ++zc) {
    int z = zc*64 + lane;
    #pragma unroll
    for (int jj = 0; jj < 4; ++jj) {
      int j = w*4 + jj;
      float2 e1r[8];
      #pragma unroll
      for (int p = 0; p < 8; ++p)
        e1r[p] = E1[(((size_t)(j*16 + kk))*8 + p)*256 + z];
      #pragma unroll
      for (int q = 0; q < 8; ++q) {
        float2 acc = make_float2(0.f,0.f);
        #pragma unroll
        for (int p = 0; p < 8; ++p) cacc(acc, o2l[j*64 + p*8 + q], e1r[p]);
        ul[lane][j*8+q] = acc;
      }
    }
    __syncthreads();
    int jq = tid & 127, zh = tid >> 7;
    for (int it = 0; it < 32; ++it) {
      int zz = zh*32 + it;
      float2 u = ul[zz][jq];
      u16 hr, lr, hi_, li_;
      bf16split(u.x, hr, lr);
      bf16split(u.y, hi_, li_);
      size_t idx = ((size_t)batch*256 + zc*64 + zz)*128 + jq;
      UH32[idx] = (unsigned)hr | ((unsigned)hi_ << 16);
      UL32[idx] = (unsigned)lr | ((unsigned)li_ << 16);
    }
    __syncthreads();
  }
}

// ---- MFMA x2t GEMM: per batch (n,kk): X1[z][x] += (U x E2)/65536 -----------
__global__ __launch_bounds__(256) void k_x2tmm(const u16* __restrict__ UH,
    const u16* __restrict__ UL, const u16* __restrict__ EH,
    const u16* __restrict__ EL, float* __restrict__ X1) {
  __shared__ u16 Ah[128][40], Al[128][40], Bhs[128][40], Bls[128][40];
  int bid = blockIdx.x;               // batch*4 + mt*2 + nt
  int batch = bid >> 2, mt = (bid >> 1) & 1, nt = bid & 1;
  int kk = batch & 15;
  int tid = threadIdx.x;
  int lane = tid & 63, wid = tid >> 6, wr = wid >> 1, wc = wid & 1;
  int r2 = tid >> 1, h2 = tid & 1;
  const u16* uhrow = UH + ((size_t)(batch*256 + mt*128 + r2))*256 + h2*16;
  const u16* ulrow = UL + ((size_t)(batch*256 + mt*128 + r2))*256 + h2*16;
  const u16* ehrow = EH + ((size_t)(kk*256 + nt*128 + r2))*256 + h2*16;
  const u16* elrow = EL + ((size_t)(kk*256 + nt*128 + r2))*256 + h2*16;
  v4f acc[4][4];
  #pragma unroll
  for (int a = 0; a < 4; ++a)
    #pragma unroll
    for (int b = 0; b < 4; ++b) acc[a][b] = (v4f){0.f, 0.f, 0.f, 0.f};
  for (int kc = 0; kc < 8; ++kc) {
    {
      const uint4* pa = (const uint4*)(uhrow + (size_t)kc*32);
      uint4 a0 = pa[0], a1 = pa[1];
      *((uint4*)&Ah[r2][h2*16])     = a0;
      *((uint4*)&Ah[r2][h2*16 + 8]) = a1;
      const uint4* pb = (const uint4*)(ulrow + (size_t)kc*32);
      uint4 b0 = pb[0], b1 = pb[1];
      *((uint4*)&Al[r2][h2*16])     = b0;
      *((uint4*)&Al[r2][h2*16 + 8]) = b1;
      const uint4* pc = (const uint4*)(ehrow + (size_t)kc*32);
      uint4 c0 = pc[0], c1 = pc[1];
      *((uint4*)&Bhs[r2][h2*16])     = c0;
      *((uint4*)&Bhs[r2][h2*16 + 8]) = c1;
      const uint4* pd = (const uint4*)(elrow + (size_t)kc*32);
      uint4 d0 = pd[0], d1 = pd[1];
      *((uint4*)&Bls[r2][h2*16])     = d0;
      *((uint4*)&Bls[r2][h2*16 + 8]) = d1;
    }
    __syncthreads();
    v8s af_h[4], af_l[4];
    int c8 = (lane >> 4) * 8;
    #pragma unroll
    for (int fi = 0; fi < 4; ++fi) {
      int row = wr*64 + fi*16 + (lane & 15);
      af_h[fi] = *(const v8s*)&Ah[row][c8];
      af_l[fi] = *(const v8s*)&Al[row][c8];
    }
    #pragma unroll
    for (int fj = 0; fj < 4; ++fj) {
      int row = wc*64 + fj*16 + (lane & 15);
      v8s bh_f = *(const v8s*)&Bhs[row][c8];
      v8s bl_f = *(const v8s*)&Bls[row][c8];
      #pragma unroll
      for (int fi = 0; fi < 4; ++fi) {
        acc[fi][fj] = __builtin_amdgcn_mfma_f32_16x16x32_bf16(af_h[fi], bh_f, acc[fi][fj], 0, 0, 0);
        acc[fi][fj] = __builtin_amdgcn_mfma_f32_16x16x32_bf16(af_l[fi], bh_f, acc[fi][fj], 0, 0, 0);
        acc[fi][fj] = __builtin_amdgcn_mfma_f32_16x16x32_bf16(af_h[fi], bl_f, acc[fi][fj], 0, 0, 0);
      }
    }
    __syncthreads();
  }
  const float sc = 1.0f/65536.0f;
  #pragma unroll
  for (int fi = 0; fi < 4; ++fi) {
    #pragma unroll
    for (int rr = 0; rr < 4; ++rr) {
      int z = mt*128 + wr*64 + fi*16 + (lane >> 4)*4 + rr;
      float* row = X1 + (size_t)batch*NPIX + (size_t)z*256 + nt*128 + wc*64 + (lane & 15);
      #pragma unroll
      for (int fj = 0; fj < 4; ++fj)
        row[fj*16] += acc[fi][fj][rr] * sc;
    }
  }
}

// ---- fused out1 + row-iFFT: block = (o, k-pair), dbuf handoff --------------
__global__ __launch_bounds__(256) void k_out1g(const float2* __restrict__ alphaR,
    const float2* __restrict__ Tt, const float2* __restrict__ A2L,
    float2* __restrict__ out1) {
  __shared__ float2 tl[2][128];
  __shared__ float sre[2][4][256], sim[2][4][256];
  int d = blockIdx.x;                 // [0, 2048)
  int xcd = d & 7, idx = d >> 3;
  int o  = xcd*32 + (idx >> 3);
  int kh = idx & 7;
  int tid = threadIdx.x, x = tid;
  int lane = tid & 63, rowi = tid >> 6;
  {
    int kk = tid >> 7, rem = tid & 127;
    int i = rem >> 3, q = rem & 7;
    tl[kk][rem] = Tt[((size_t)((i*16 + 2*kh + kk)*8 + q))*256 + o];
  }
  float2 tw[8];
  make_tw(+1.0f, lane, tw);
  __syncthreads();
  float2 g0[16], g1[16];
  #pragma unroll
  for (int i = 0; i < 16; ++i) {
    const float2* a2k0 = &A2L[((size_t)((i*16 + 2*kh + 0)*8))*256 + x];
    const float2* a2k1 = &A2L[((size_t)((i*16 + 2*kh + 1)*8))*256 + x];
    float2 acc0 = make_float2(0.f, 0.f), acc1 = make_float2(0.f, 0.f);
    #pragma unroll
    for (int q = 0; q < 8; ++q) {
      cacc(acc0, tl[0][i*8+q], a2k0[(size_t)q*256]);
      cacc(acc1, tl[1][i*8+q], a2k1[(size_t)q*256]);
    }
    g0[i] = acc0; g1[i] = acc1;
  }
  const float2* arow = alphaR + (size_t)o*128*256 + x;
  float2 arA[16], arB[16];
  #pragma unroll
  for (int i = 0; i < 16; ++i) arA[i] = arow[(size_t)(0*16 + i)*256];
  #pragma unroll
  for (int i = 0; i < 16; ++i) arB[i] = arow[(size_t)(1*16 + i)*256];
  for (int bp = 0; bp < 4; ++bp) {
    int pb = bp & 1;
    float2 acc0 = make_float2(0.f,0.f), acc1 = acc0, acc2 = acc0, acc3 = acc0;
    #pragma unroll
    for (int i = 0; i < 16; ++i) {
      cacc(acc0, arA[i], g0[i]);
      cacc(acc1, arA[i], g1[i]);
      cacc(acc2, arB[i], g0[i]);
      cacc(acc3, arB[i], g1[i]);
    }
    sre[pb][0][x] = acc0.x; sim[pb][0][x] = acc0.y;
    sre[pb][1][x] = acc1.x; sim[pb][1][x] = acc1.y;
    sre[pb][2][x] = acc2.x; sim[pb][2][x] = acc2.y;
    sre[pb][3][x] = acc3.x; sim[pb][3][x] = acc3.y;
    __syncthreads();
    if (bp < 3) {
      int b0 = (bp+1)*2, b1 = b0 + 1;
      #pragma unroll
      for (int i = 0; i < 16; ++i) arA[i] = arow[(size_t)(b0*16 + i)*256];
      #pragma unroll
      for (int i = 0; i < 16; ++i) arB[i] = arow[(size_t)(b1*16 + i)*256];
    }
    float2 v0 = make_float2(sre[pb][rowi][lane],     sim[pb][rowi][lane]);
    float2 v1 = make_float2(sre[pb][rowi][64+lane],  sim[pb][rowi][64+lane]);
    float2 v2 = make_float2(sre[pb][rowi][128+lane], sim[pb][rowi][128+lane]);
    float2 v3 = make_float2(sre[pb][rowi][192+lane], sim[pb][rowi][192+lane]);
    ifft256_reg(v0, v1, v2, v3, lane, tw);
    int img = (bp*2 + (rowi >> 1))*16 + 2*kh + (rowi & 1);
    float2* op = out1 + ((size_t)img*256 + o)*256;
    nts2(&op[lane], v0); nts2(&op[64+lane], v1);
    nts2(&op[128+lane], v2); nts2(&op[192+lane], v3);
  }
}

// ---------------- final: inorm(x1pre) + w0conv(v) -> fc1 -> sin -> fc2 ------
__global__ __launch_bounds__(256) void k_final(const float* __restrict__ x,
    const float* __restrict__ x1pre, const float2* __restrict__ stats2,
    const float* __restrict__ fc0w, const float* __restrict__ fc0b,
    const float* __restrict__ w0w, const float* __restrict__ w0b,
    const float* __restrict__ fc1w, const float* __restrict__ fc1b,
    const float* __restrict__ fc2w, const float* __restrict__ fc2b,
    float* __restrict__ out) {
  __shared__ float s_fc1w[2048], s_fc1b[128], s_fc2w[384], s_w0w[256], s_w0b[16], s_fc2b[3];
  int tid = threadIdx.x;
  for (int e = 0; e < 8; ++e) s_fc1w[tid + 256*e] = fc1w[tid + 256*e];
  if (tid < 128) s_fc1b[tid] = fc1b[tid];
  for (int e = 0; e < 2; ++e) { int q = tid + 256*e; if (q < 384) s_fc2w[q] = fc2w[q]; }
  s_w0w[tid] = w0w[tid];
  if (tid < 16) s_w0b[tid] = w0b[tid];
  if (tid < 3)  s_fc2b[tid] = fc2b[tid];
  __syncthreads();

  int bid = blockIdx.x;               // b*256 + h
  int hh = bid & 255, b = bid >> 8;
  int ww = tid;
  size_t pix = (size_t)hh*256 + ww;
  float xc0 = x[((size_t)b*3 + 0)*NPIX + pix];
  float xc1 = x[((size_t)b*3 + 1)*NPIX + pix];
  float xc2 = x[((size_t)b*3 + 2)*NPIX + pix];
  float gx = hh*(1.0f/255.0f), gy = ww*(1.0f/255.0f);
  float v[16], x1n[16], uo[16];
  #pragma unroll
  for (int k = 0; k < 16; ++k)
    v[k] = fc0b[k] + xc0*fc0w[k] + xc1*fc0w[16+k] + xc2*fc0w[32+k] + gx*fc0w[48+k] + gy*fc0w[64+k];
  #pragma unroll
  for (int k = 0; k < 16; ++k) {
    float2 st = stats2[b*16 + k];
    float xv = x1pre[((size_t)(b*16 + k))*NPIX + pix];
    x1n[k] = (xv - st.x)*st.y;
  }
  #pragma unroll
  for (int o = 0; o < 16; ++o) {
    float acc = s_w0b[o];
    #pragma unroll
    for (int k = 0; k < 16; ++k) acc = fmaf(v[k], s_w0w[o*16+k], acc);
    uo[o] = acc + x1n[o];
  }
  float o0 = 0.f, o1 = 0.f, o2 = 0.f;
  for (int jj = 0; jj < 128; ++jj) {
    float t = s_fc1b[jj];
    #pragma unroll
    for (int k = 0; k < 16; ++k) t = fmaf(uo[k], s_fc1w[k*128 + jj], t);
    float s = __sinf(t);
    o0 = fmaf(s, s_fc2w[jj*3+0], o0);
    o1 = fmaf(s, s_fc2w[jj*3+1], o1);
    o2 = fmaf(s, s_fc2w[jj*3+2], o2);
  }
  out[((size_t)b*3 + 0)*NPIX + pix] = o0 + s_fc2b[0];
  out[((size_t)b*3 + 1)*NPIX + pix] = o1 + s_fc2b[1];
  out[((size_t)b*3 + 2)*NPIX + pix] = o2 + s_fc2b[2];
}

// ---------------------------------------------------------------------------
extern "C" void kernel_launch(void* const* d_in, const int* in_sizes, int n_in,
                              void* d_out, int out_size, void* d_ws, size_t ws_size,
                              hipStream_t stream) {
  const float*  x    = (const float*)d_in[0];
  const float*  fc0w = (const float*)d_in[1];
  const float*  fc0b = (const float*)d_in[2];
  const float2* p1   = (const float2*)d_in[3];
  const float2* p2   = (const float2*)d_in[4];
  const float2* res  = (const float2*)d_in[5];
  const float*  w0w  = (const float*)d_in[6];
  const float*  w0b  = (const float*)d_in[7];
  const float*  fc1w = (const float*)d_in[8];
  const float*  fc1b = (const float*)d_in[9];
  const float*  fc2w = (const float*)d_in[10];
  const float*  fc2b = (const float*)d_in[11];
  const float*  txv  = (const float*)d_in[12];
  const float*  tyv  = (const float*)d_in[13];
  float* out = (float*)d_out;

  // workspace layout (bytes); NEED == proven-safe 252,774,400
  const size_t OFF_A1   = 0;            // 4 MiB
  const size_t OFF_A2T  = 4194304;      // 4 MiB
  const size_t OFF_E1   = 8388608;      // 4 MiB
  const size_t OFF_E2   = 12582912;     // 4 MiB
  const size_t OFF_ST1  = 16777216;
  const size_t OFF_ST2  = 16778240;
  const size_t OFF_OUT2 = 16779264;     // 64 KiB
  const size_t OFF_MT   = 16844800;     // 1 MiB (Mt; later stats-p partials)
  const size_t OFF_S    = 17893376;     // 32 MiB (stats-v partials; S; later UH+UL)
  const size_t OFF_X1   = 51447808;     // 32 MiB (Tt early; X1 later)
  const size_t OFF_A    = 85002240;     // 64 MiB (row-fft; out1 row-ifft'd)
  const size_t OFF_B    = 152111104;    // 64 MiB (alphaR o-major)
  const size_t OFF_G    = 219219968;    // 32 MiB (A2L 4 + BH 4 + BL 4 + EH 2 + EL 2)
  const size_t NEED     = 252774400;
  if (ws_size < NEED) return;
  char* ws = (char*)d_ws;
  float2* A1  = (float2*)(ws + OFF_A1);
  float2* A2T = (float2*)(ws + OFF_A2T);
  float2* E1  = (float2*)(ws + OFF_E1);
  float2* E2  = (float2*)(ws + OFF_E2);
  float2* st1 = (float2*)(ws + OFF_ST1);
  float2* st2 = (float2*)(ws + OFF_ST2);
  float2* o2b = (float2*)(ws + OFF_OUT2);
  float2* Mt  = (float2*)(ws + OFF_MT);
  float2* Sb  = (float2*)(ws + OFF_S);
  float2* Tt  = (float2*)(ws + OFF_X1);
  float*  X1  = (float*)(ws + OFF_X1);
  float2* Ab  = (float2*)(ws + OFF_A);
  float2* Bb  = (float2*)(ws + OFF_B);
  float2* A2L = (float2*)(ws + OFF_G);
  u16*    BH  = (u16*)(ws + OFF_G + 4194304);
  u16*    BL  = (u16*)(ws + OFF_G + 8388608);
  unsigned* EH32 = (unsigned*)(ws + OFF_G + 12582912);   // 2 MiB
  unsigned* EL32 = (unsigned*)(ws + OFF_G + 14680064);   // 2 MiB
  unsigned* UH32 = (unsigned*)(ws + OFF_S);              // 16 MiB (S dead after k_Mt)
  unsigned* UL32 = (unsigned*)(ws + OFF_S + 16777216);   // 16 MiB

  k_setup  <<<2048, 256, 0, stream>>>(p1, p2, txv, tyv, A1, A2T, A2L, E1, E2);
  k_B      <<<128, 256, 0, stream>>>(A2T, BH, BL);
  k_E2s    <<<16, 256, 0, stream>>>(E2, EH32, EL32);
  k_T      <<<256, 256, 0, stream>>>(res, A1, Tt);
  k_stats_v_part<<<1024, 256, 0, stream>>>(x, fc0w, fc0b, Sb);
  k_stats_fin   <<<1, 256, 0, stream>>>(Sb, st1, 128);
  // forward fft2
  k_fft_v  <<<8192, 256, 0, stream>>>(x, fc0w, fc0b, st1, Ab);
  k_fft_colR<<<2048, 256, 0, stream>>>(Ab, Bb);                 // Bb = alphaR
  // pole-residue spectral sums (MFMA)
  k_Smm    <<<512, 256, 0, stream>>>(Bb, BH, BL, (float*)Sb);
  k_Mt     <<<2048, 256, 0, stream>>>(Sb, A1, Mt);
  k_out2   <<<32, 256, 0, stream>>>(Mt, res, o2b);
  // transient: U build (into dead S region, split bf16)
  k_Umm    <<<128, 256, 0, stream>>>(o2b, E1, UH32, UL32);
  // fused out1 + row-iFFT
  k_out1g  <<<2048, 256, 0, stream>>>(Bb, Tt, A2L, Ab);
  // inverse column FFT -> X1
  k_ifft_col_real<<<2048, 256, 0, stream>>>(Ab, X1, 1.0f/65536.0f);
  // transient GEMM: X1 += U x E2 / 65536
  k_x2tmm  <<<512, 256, 0, stream>>>((const u16*)UH32, (const u16*)UL32,
                                     (const u16*)EH32, (const u16*)EL32, X1);
  // second instance norm (partials in dead Mt region) + heads
  k_stats_p_part<<<1024, 256, 0, stream>>>(X1, Mt);
  k_stats_fin   <<<1, 256, 0, stream>>>(Mt, st2, 128);
  k_final  <<<2048, 256, 0, stream>>>(x, X1, st2, fc0w, fc0b,
                                      w0w, w0b, fc1w, fc1b, fc2w, fc2b, out);
}

// Round 17
// 494.776 us; speedup vs baseline: 1.0508x; 1.0146x over previous
//
#include <hip/hip_runtime.h>
#include <cstddef>

#define NPIX 65536
#define PI_F 3.14159265358979323846f

typedef float v4f __attribute__((ext_vector_type(4)));
typedef short v8s __attribute__((ext_vector_type(8)));
typedef unsigned short u16;

__device__ __forceinline__ void cacc(float2& acc, float2 a, float2 b) {
  acc.x = fmaf(a.x, b.x, fmaf(-a.y, b.y, acc.x));
  acc.y = fmaf(a.x, b.y, fmaf(a.y, b.x, acc.y));
}
__device__ __forceinline__ float2 cmulf(float2 a, float2 b) {
  return make_float2(a.x*b.x - a.y*b.y, a.x*b.y + a.y*b.x);
}
__device__ __forceinline__ float2 add2(float2 a, float2 b) { return make_float2(a.x+b.x, a.y+b.y); }
__device__ __forceinline__ float2 sub2(float2 a, float2 b) { return make_float2(a.x-b.x, a.y-b.y); }
__device__ __forceinline__ float2 shflc(float2 v, int mask) {
  return make_float2(__shfl_xor(v.x, mask), __shfl_xor(v.y, mask));
}
__device__ __forceinline__ void nts2(float2* p, float2 v) {
  __builtin_nontemporal_store(*reinterpret_cast<const double*>(&v),
                              reinterpret_cast<double*>(p));
}
__device__ __forceinline__ void nts1(float* p, float v) {
  __builtin_nontemporal_store(v, p);
}
__device__ __forceinline__ void bf16split(float v, u16& h, u16& l) {
  unsigned bits = __float_as_uint(v);
  h = (u16)(bits >> 16);
  float r = v - __uint_as_float((unsigned)h << 16);
  l = (u16)(__float_as_uint(r) >> 16);
}
__device__ __forceinline__ void make_tw(float sgn, int l, float2* tw) {
  const float c = sgn * (2.0f*PI_F/256.0f);
  int idxs[8] = { l, 64+l, 2*l, (l&31)<<2, (l&15)<<3, (l&7)<<4, (l&3)<<5, (l&1)<<6 };
  #pragma unroll
  for (int r = 0; r < 8; ++r) { float sn, cs; __sincosf(c*idxs[r], &sn, &cs); tw[r] = make_float2(cs, sn); }
}
__device__ __forceinline__ void fwd_stage(float2& vv, int lane, int H, float2 tws, bool unit) {
  float2 p = shflc(vv, H);
  bool up = (lane & H) != 0;
  float2 lo = add2(vv, p);
  float2 df = sub2(p, vv);
  float2 hi = unit ? df : cmulf(df, tws);
  vv = up ? hi : lo;
}
__device__ __forceinline__ void inv_stage(float2& vv, int lane, int H, float2 tws, bool unit) {
  float2 p = shflc(vv, H);
  bool up = (lane & H) != 0;
  float2 bv = up ? vv : p;
  float2 av = up ? p : vv;
  float2 t = unit ? bv : cmulf(bv, tws);
  vv = up ? sub2(av, t) : add2(av, t);
}
__device__ __forceinline__ void ifft256_reg(float2& v0, float2& v1, float2& v2,
    float2& v3, int lane, const float2* tw) {
  inv_stage(v0, lane, 1, tw[0], true ); inv_stage(v1, lane, 1, tw[0], true );
  inv_stage(v2, lane, 1, tw[0], true ); inv_stage(v3, lane, 1, tw[0], true );
  inv_stage(v0, lane, 2, tw[7], false); inv_stage(v1, lane, 2, tw[7], false);
  inv_stage(v2, lane, 2, tw[7], false); inv_stage(v3, lane, 2, tw[7], false);
  inv_stage(v0, lane, 4, tw[6], false); inv_stage(v1, lane, 4, tw[6], false);
  inv_stage(v2, lane, 4, tw[6], false); inv_stage(v3, lane, 4, tw[6], false);
  inv_stage(v0, lane, 8, tw[5], false); inv_stage(v1, lane, 8, tw[5], false);
  inv_stage(v2, lane, 8, tw[5], false); inv_stage(v3, lane, 8, tw[5], false);
  inv_stage(v0, lane, 16, tw[4], false); inv_stage(v1, lane, 16, tw[4], false);
  inv_stage(v2, lane, 16, tw[4], false); inv_stage(v3, lane, 16, tw[4], false);
  inv_stage(v0, lane, 32, tw[3], false); inv_stage(v1, lane, 32, tw[3], false);
  inv_stage(v2, lane, 32, tw[3], false); inv_stage(v3, lane, 32, tw[3], false);
  { float2 t01 = cmulf(v1, tw[2]); float2 n0 = add2(v0, t01), n1 = sub2(v0, t01);
    float2 t23 = cmulf(v3, tw[2]); float2 n2 = add2(v2, t23), n3 = sub2(v2, t23);
    v0 = n0; v1 = n1; v2 = n2; v3 = n3; }
  { float2 t02 = cmulf(v2, tw[0]); float2 n0 = add2(v0, t02), n2 = sub2(v0, t02);
    float2 t13 = cmulf(v3, tw[1]); float2 n1 = add2(v1, t13), n3 = sub2(v1, t13);
    v0 = n0; v2 = n2; v1 = n1; v3 = n3; }
}

// ---------------- setup: A1, A2T, A2L (brev-x domain), E1, E2 ---------------
__global__ __launch_bounds__(256) void k_setup(const float2* __restrict__ p1,
    const float2* __restrict__ p2, const float* __restrict__ txv,
    const float* __restrict__ tyv, float2* __restrict__ A1,
    float2* __restrict__ A2T, float2* __restrict__ A2L,
    float2* __restrict__ E1, float2* __restrict__ E2) {
  int gid = blockIdx.x*256 + threadIdx.x;          // [0, 524288)
  int o = gid & 255, p = (gid>>8)&7, k = (gid>>11)&15, i = gid>>15;
  float ko = (o < 128) ? (float)o : (float)(o - 256);
  float dty = tyv[1] - tyv[0];
  float dtx = txv[1] - txv[0];
  const float TWO_PI = 6.283185307179586f;
  {
    float lam = TWO_PI * ko / (256.0f * dty);
    float2 pv = p1[(i*16+k)*8 + p];
    float xr = -pv.x, yi = lam - pv.y;
    float D = xr*xr + yi*yi;
    A1[((size_t)((i*16+k)*8 + p))*256 + o] = make_float2(xr/D, -yi/D);
    float tv = tyv[o];
    float m = expf(pv.x*tv);
    E1[((size_t)((i*16+k)*8 + p))*256 + o] = make_float2(m*cosf(pv.y*tv), m*sinf(pv.y*tv));
  }
  {
    int fo = __brev((unsigned)o) >> 24;
    float ko2 = (fo < 128) ? (float)fo : (float)(fo - 256);
    float lam = TWO_PI * ko2 / (256.0f * dtx);
    float2 pv = p2[(i*16+k)*8 + p];
    float xr = -pv.x, yi = lam - pv.y;
    float D = xr*xr + yi*yi;
    float2 val = make_float2(xr/D, -yi/D);
    A2T[((size_t)i*256 + o)*128 + k*8 + p] = val;
    A2L[((size_t)((i*16+k)*8 + p))*256 + o] = val;
    float tv = txv[o];
    float m = expf(pv.x*tv);
    E2[((size_t)((i*16+k)*8 + p))*256 + o] = make_float2(m*cosf(pv.y*tv), m*sinf(pv.y*tv));
  }
}

// ---- build BT_big (bf16 hi/lo) from A2T:  BT[i][n2][k2] --------------------
__global__ __launch_bounds__(256) void k_B(const float2* __restrict__ A2T,
    u16* __restrict__ BH, u16* __restrict__ BL) {
  int bid = blockIdx.x;               // i*8 + g
  int i = bid >> 3, g = bid & 7;
  int tid = threadIdx.x;
  int n2 = g*32 + (tid >> 3);
  int kq = n2 >> 1, par = n2 & 1;
  int x0 = (tid & 7) * 32;
  size_t outb = ((size_t)i*256 + n2)*512;
  for (int xx = 0; xx < 32; ++xx) {
    int x = x0 + xx;
    float2 a2 = A2T[((size_t)i*256 + x)*128 + kq];
    float v0 = par ? a2.y : a2.x;
    float v1 = par ? a2.x : -a2.y;
    u16 h0, l0, h1, l1;
    bf16split(v0, h0, l0);
    bf16split(v1, h1, l1);
    BH[outb + 2*x]     = h0;  BL[outb + 2*x]     = l0;
    BH[outb + 2*x + 1] = h1;  BL[outb + 2*x + 1] = l1;
  }
}

// ---- split E2 -> EH/EL [kk][x][k2], k2 = 2jq (+Re) / 2jq+1 (-Im) -----------
__global__ __launch_bounds__(256) void k_E2s(const float2* __restrict__ E2,
    unsigned* __restrict__ EH32, unsigned* __restrict__ EL32) {
  int kk = blockIdx.x;
  int x = threadIdx.x;
  for (int jq = 0; jq < 128; ++jq) {
    int j = jq >> 3, q = jq & 7;
    float2 e2 = E2[(((size_t)(j*16 + kk))*8 + q)*256 + x];
    u16 h0,l0,h1,l1;
    bf16split(e2.x, h0, l0);
    bf16split(-e2.y, h1, l1);
    size_t idx = ((size_t)kk*256 + x)*128 + jq;
    EH32[idx] = (unsigned)h0 | ((unsigned)h1 << 16);
    EL32[idx] = (unsigned)l0 | ((unsigned)l1 << 16);
  }
}

// ---------------- T[ik][q][o] = sum_p res[ik][p][q] A1[ik][p][o] ------------
__global__ __launch_bounds__(256) void k_T(const float2* __restrict__ res,
    const float2* __restrict__ A1, float2* __restrict__ Tt) {
  int ik = blockIdx.x, tid = threadIdx.x;
  __shared__ float2 rbuf[64];
  __shared__ float2 a1[8][256];
  if (tid < 64) rbuf[tid] = res[(size_t)ik*64 + tid];
  for (int e = 0; e < 8; ++e) {
    int lin = tid + 256*e;
    int p = lin >> 8, o = lin & 255;
    a1[p][o] = A1[((size_t)ik*8 + p)*256 + o];
  }
  __syncthreads();
  int o = tid;
  #pragma unroll
  for (int q = 0; q < 8; ++q) {
    float2 acc = make_float2(0.f, 0.f);
    #pragma unroll
    for (int p = 0; p < 8; ++p) cacc(acc, rbuf[p*8+q], a1[p][o]);
    Tt[((size_t)ik*8 + q)*256 + o] = acc;
  }
}

// ---- stats partials of v (recomputed from x) -------------------------------
__global__ __launch_bounds__(256) void k_stats_v_part(const float* __restrict__ x,
    const float* __restrict__ fc0w, const float* __restrict__ fc0b,
    float2* __restrict__ part) {
  int bid = blockIdx.x;               // img*8 + seg
  int seg = bid & 7, img = bid >> 3;
  int k = img & 15, b = img >> 4;
  int tid = threadIdx.x;
  float w0 = fc0w[k], w1 = fc0w[16+k], w2 = fc0w[32+k], w3 = fc0w[48+k], w4 = fc0w[64+k];
  float base = fc0b[k] + (tid*(1.0f/255.0f))*w4;
  const float* xb = x + (size_t)b*3*NPIX + (size_t)seg*8192;
  float s = 0.f, s2 = 0.f;
  for (int it = 0; it < 32; ++it) {
    int row = seg*32 + it;
    int p = it*256 + tid;
    float val = base + (row*(1.0f/255.0f))*w3 + xb[p]*w0 + xb[NPIX+p]*w1 + xb[2*NPIX+p]*w2;
    s += val; s2 += val*val;
  }
  __shared__ float rs[256], rq[256];
  rs[tid] = s; rq[tid] = s2;
  __syncthreads();
  for (int off = 128; off > 0; off >>= 1) {
    if (tid < off) { rs[tid] += rs[tid+off]; rq[tid] += rq[tid+off]; }
    __syncthreads();
  }
  if (tid == 0) part[bid] = make_float2(rs[0], rq[0]);
}

// ---- combine nper partials per img -> stats --------------------------------
__global__ __launch_bounds__(256) void k_stats_fin(const float2* __restrict__ part,
    float2* __restrict__ stats, int nimg, int nper) {
  int img = blockIdx.x*256 + threadIdx.x;
  if (img >= nimg) return;
  float s = 0.f, s2 = 0.f;
  for (int e = 0; e < nper; ++e) { float2 v = part[img*nper + e]; s += v.x; s2 += v.y; }
  float mean = s * (1.0f/65536.0f);
  float var  = s2 * (1.0f/65536.0f) - mean*mean;
  stats[img] = make_float2(mean, rsqrtf(var + 1e-5f));
}

// ---- row FFT of normalized v, in-register DIF (brev-x out) -----------------
__global__ __launch_bounds__(256) void k_fft_v(const float* __restrict__ x,
    const float* __restrict__ fc0w, const float* __restrict__ fc0b,
    const float2* __restrict__ stats, float2* __restrict__ out) {
  int tid = threadIdx.x, lane = tid & 63, rowi = tid >> 6;
  int bid = blockIdx.x;
  int img = bid >> 6;
  int h   = (bid & 63)*4 + rowi;
  int k = img & 15, b = img >> 4;
  float2 st = stats[img];
  float w0 = fc0w[k], w1 = fc0w[16+k], w2 = fc0w[32+k], w3 = fc0w[48+k], w4 = fc0w[64+k];
  float bb = fc0b[k] + (h*(1.0f/255.0f))*w3;
  const float* xb = x + (size_t)b*3*NPIX + (size_t)h*256;
  float2 tw[8];
  make_tw(-1.0f, lane, tw);
  float2 v0, v1, v2, v3;
  {
    #pragma unroll
    for (int e = 0; e < 4; ++e) {
      int j = e*64 + lane;
      float val = bb + (j*(1.0f/255.0f))*w4 + xb[j]*w0 + xb[NPIX+j]*w1 + xb[2*NPIX+j]*w2;
      val = (val - st.x)*st.y;
      float2 c = make_float2(val, 0.f);
      if (e == 0) v0 = c; else if (e == 1) v1 = c; else if (e == 2) v2 = c; else v3 = c;
    }
  }
  { float2 n0 = add2(v0, v2), n2 = cmulf(sub2(v0, v2), tw[0]);
    float2 n1 = add2(v1, v3), n3 = cmulf(sub2(v1, v3), tw[1]);
    v0 = n0; v1 = n1; v2 = n2; v3 = n3; }
  { float2 n0 = add2(v0, v1), n1 = cmulf(sub2(v0, v1), tw[2]);
    float2 n2 = add2(v2, v3), n3 = cmulf(sub2(v2, v3), tw[2]);
    v0 = n0; v1 = n1; v2 = n2; v3 = n3; }
  fwd_stage(v0, lane, 32, tw[3], false); fwd_stage(v1, lane, 32, tw[3], false);
  fwd_stage(v2, lane, 32, tw[3], false); fwd_stage(v3, lane, 32, tw[3], false);
  fwd_stage(v0, lane, 16, tw[4], false); fwd_stage(v1, lane, 16, tw[4], false);
  fwd_stage(v2, lane, 16, tw[4], false); fwd_stage(v3, lane, 16, tw[4], false);
  fwd_stage(v0, lane,  8, tw[5], false); fwd_stage(v1, lane,  8, tw[5], false);
  fwd_stage(v2, lane,  8, tw[5], false); fwd_stage(v3, lane,  8, tw[5], false);
  fwd_stage(v0, lane,  4, tw[6], false); fwd_stage(v1, lane,  4, tw[6], false);
  fwd_stage(v2, lane,  4, tw[6], false); fwd_stage(v3, lane,  4, tw[6], false);
  fwd_stage(v0, lane,  2, tw[7], false); fwd_stage(v1, lane,  2, tw[7], false);
  fwd_stage(v2, lane,  2, tw[7], false); fwd_stage(v3, lane,  2, tw[7], false);
  fwd_stage(v0, lane,  1, tw[0], true ); fwd_stage(v1, lane,  1, tw[0], true );
  fwd_stage(v2, lane,  1, tw[0], true ); fwd_stage(v3, lane,  1, tw[0], true );
  float2* op = out + ((size_t)img*256 + h)*256;
  nts2(&op[lane], v0); nts2(&op[64+lane], v1);
  nts2(&op[128+lane], v2); nts2(&op[192+lane], v3);
}

// ---- forward column FFT, writes o-major alphaR[o][img][x] ------------------
__global__ __launch_bounds__(256) void k_fft_colR(const float2* __restrict__ in,
    float2* __restrict__ outp) {
  __shared__ float tr[256][17], tim[256][17];
  __shared__ float twr[128], twi[128];
  int tid = threadIdx.x;
  int c = tid & 15, g = tid >> 4;
  int img = blockIdx.x >> 4;
  int c0  = (blockIdx.x & 15) * 16;
  if (tid < 128) {
    float ang = (PI_F/128.0f)*tid;
    twr[tid] = cosf(ang); twi[tid] = -sinf(ang);
  }
  const float2* base = in + (size_t)img*NPIX + c0;
  #pragma unroll
  for (int it = 0; it < 16; ++it) {
    int row = it*16 + g;
    float2 v = base[(size_t)row*256 + c];
    int br = __brev((unsigned)row) >> 24;
    tr[br][c] = v.x; tim[br][c] = v.y;
  }
  __syncthreads();
  int lane = tid & 63, w = tid >> 6;
  int cw = w*4 + (lane >> 4);
  int gw = lane & 15;
  for (int s = 0; s < 8; ++s) {
    __builtin_amdgcn_wave_barrier();
    int half = 1 << s;
    #pragma unroll
    for (int r = 0; r < 8; ++r) {
      int m  = gw + 16*r;
      int t  = m & (half - 1);
      int grp = m >> s;
      int i0 = (grp << (s+1)) + t;
      int i1 = i0 + half;
      int twx = t << (7 - s);
      float wr = twr[twx], wi = twi[twx];
      float br = tr[i1][cw], bi = tim[i1][cw];
      float vr = br*wr - bi*wi, vi = br*wi + bi*wr;
      float ar = tr[i0][cw], ai = tim[i0][cw];
      tr[i0][cw] = ar + vr; tim[i0][cw] = ai + vi;
      tr[i1][cw] = ar - vr; tim[i1][cw] = ai - vi;
    }
  }
  __syncthreads();
  #pragma unroll
  for (int it = 0; it < 16; ++it) {
    int row = it*16 + g;
    float2 vv = make_float2(tr[row][c], tim[row][c]);
    nts2(&outp[((size_t)row*128 + img)*256 + c0 + c], vv);
  }
}

// ---------------- column inverse FFT, write real part to out ---------------
__global__ __launch_bounds__(256) void k_ifft_col_real(const float2* __restrict__ in,
    float* __restrict__ outp, float scale) {
  __shared__ float tr[256][17], tim[256][17];
  __shared__ float twr[128], twi[128];
  int tid = threadIdx.x;
  int c = tid & 15, g = tid >> 4;
  int img = blockIdx.x >> 4;
  int c0  = (blockIdx.x & 15) * 16;
  if (tid < 128) {
    float ang = (PI_F/128.0f)*tid;
    twr[tid] = cosf(ang); twi[tid] = sinf(ang);
  }
  const float2* base = in + (size_t)img*NPIX + c0;
  #pragma unroll
  for (int it = 0; it < 16; ++it) {
    int row = it*16 + g;
    float2 v = base[(size_t)row*256 + c];
    int br = __brev((unsigned)row) >> 24;
    tr[br][c] = v.x; tim[br][c] = v.y;
  }
  __syncthreads();
  int lane = tid & 63, w = tid >> 6;
  int cw = w*4 + (lane >> 4);
  int gw = lane & 15;
  for (int s = 0; s < 8; ++s) {
    __builtin_amdgcn_wave_barrier();
    int half = 1 << s;
    #pragma unroll
    for (int r = 0; r < 8; ++r) {
      int m  = gw + 16*r;
      int t  = m & (half - 1);
      int grp = m >> s;
      int i0 = (grp << (s+1)) + t;
      int i1 = i0 + half;
      int twx = t << (7 - s);
      float wr = twr[twx], wi = twi[twx];
      float br = tr[i1][cw], bi = tim[i1][cw];
      float vr = br*wr - bi*wi, vi = br*wi + bi*wr;
      float ar = tr[i0][cw], ai = tim[i0][cw];
      tr[i0][cw] = ar + vr; tim[i0][cw] = ai + vi;
      tr[i1][cw] = ar - vr; tim[i1][cw] = ai - vi;
    }
  }
  __syncthreads();
  float* ob = outp + (size_t)img*NPIX + c0;
  #pragma unroll
  for (int it = 0; it < 16; ++it) {
    int row = it*16 + g;
    nts1(&ob[(size_t)row*256 + c], tr[row][c]*scale);
  }
}

// ---- MFMA S-GEMM: per i, S_real[2048][256] = A_real[2048][512] x B[512][256]
__global__ __launch_bounds__(256) void k_Smm(const float2* __restrict__ alphaR,
    const u16* __restrict__ BH, const u16* __restrict__ BL,
    float* __restrict__ Sf) {
  __shared__ u16 Ah[128][40], Al[128][40], Bhs[128][40], Bls[128][40];
  int bid = blockIdx.x;               // i*32 + mt*2 + nt
  int i = bid >> 5, rem = bid & 31, mt = rem >> 1, nt = rem & 1;
  int tid = threadIdx.x;
  int lane = tid & 63, wid = tid >> 6, wr = wid >> 1, wc = wid & 1;
  int r2 = tid >> 1, h2 = tid & 1;
  int m_s = mt*128 + r2;
  const float2* arow = alphaR + ((size_t)((m_s & 255)*128) + (size_t)((m_s >> 8)*16 + i))*256 + h2*8;
  const u16* bhrow = BH + ((size_t)i*256 + nt*128 + r2)*512 + h2*16;
  const u16* blrow = BL + ((size_t)i*256 + nt*128 + r2)*512 + h2*16;
  v4f acc[4][4];
  #pragma unroll
  for (int a = 0; a < 4; ++a)
    #pragma unroll
    for (int b = 0; b < 4; ++b) acc[a][b] = (v4f){0.f, 0.f, 0.f, 0.f};
  for (int kc = 0; kc < 16; ++kc) {
    const float2* ap = arow + kc*16;
    #pragma unroll
    for (int e = 0; e < 8; ++e) {
      float2 v = ap[e];
      u16 hr, lr, hi_, li_;
      bf16split(v.x, hr, lr);
      bf16split(v.y, hi_, li_);
      int c = h2*16 + 2*e;
      Ah[r2][c] = hr; Ah[r2][c+1] = hi_;
      Al[r2][c] = lr; Al[r2][c+1] = li_;
    }
    {
      const uint4* ph = (const uint4*)(bhrow + (size_t)kc*32);
      uint4 q0 = ph[0], q1 = ph[1];
      *((uint4*)&Bhs[r2][h2*16])     = q0;
      *((uint4*)&Bhs[r2][h2*16 + 8]) = q1;
      const uint4* pl = (const uint4*)(blrow + (size_t)kc*32);
      uint4 s0 = pl[0], s1 = pl[1];
      *((uint4*)&Bls[r2][h2*16])     = s0;
      *((uint4*)&Bls[r2][h2*16 + 8]) = s1;
    }
    __syncthreads();
    v8s af_h[4], af_l[4];
    int c8 = (lane >> 4) * 8;
    #pragma unroll
    for (int fi = 0; fi < 4; ++fi) {
      int row = wr*64 + fi*16 + (lane & 15);
      af_h[fi] = *(const v8s*)&Ah[row][c8];
      af_l[fi] = *(const v8s*)&Al[row][c8];
    }
    #pragma unroll
    for (int fj = 0; fj < 4; ++fj) {
      int row = wc*64 + fj*16 + (lane & 15);
      v8s bh_f = *(const v8s*)&Bhs[row][c8];
      v8s bl_f = *(const v8s*)&Bls[row][c8];
      #pragma unroll
      for (int fi = 0; fi < 4; ++fi) {
        acc[fi][fj] = __builtin_amdgcn_mfma_f32_16x16x32_bf16(af_h[fi], bh_f, acc[fi][fj], 0, 0, 0);
        acc[fi][fj] = __builtin_amdgcn_mfma_f32_16x16x32_bf16(af_l[fi], bh_f, acc[fi][fj], 0, 0, 0);
        acc[fi][fj] = __builtin_amdgcn_mfma_f32_16x16x32_bf16(af_h[fi], bl_f, acc[fi][fj], 0, 0, 0);
      }
    }
    __syncthreads();
  }
  #pragma unroll
  for (int fi = 0; fi < 4; ++fi) {
    #pragma unroll
    for (int rr = 0; rr < 4; ++rr) {
      int m = mt*128 + wr*64 + fi*16 + (lane >> 4)*4 + rr;
      int n = m >> 8, o = m & 255;
      float* srow = Sf + ((size_t)(n*16 + i)*256 + o)*256 + nt*128 + wc*64 + (lane & 15);
      #pragma unroll
      for (int fj = 0; fj < 4; ++fj)
        nts1(&srow[fj*16], acc[fi][fj][rr]);
    }
  }
}

// ---------------- Mt[n,i,k,p,q] = sum_o S[n,i,o,(k,q)] A1[i,k,p,o] ----------
__global__ __launch_bounds__(256) void k_Mt(const float2* __restrict__ S,
    const float2* __restrict__ A1, float2* __restrict__ Mt) {
  __shared__ float2 sl[8][258];
  __shared__ float2 a1l[8][258];
  __shared__ float2 part[4][64];
  int bid = blockIdx.x;               // (n*16+i)*16 + k
  int k = bid & 15, ni = bid >> 4;
  int i = ni & 15;
  int ik = i*16 + k;
  int tid = threadIdx.x;
  for (int e = 0; e < 8; ++e) {
    int lin = tid + 256*e;
    int o = lin >> 3, q = lin & 7;
    sl[q][o] = S[((size_t)ni*256 + o)*128 + k*8 + q];
  }
  for (int e = 0; e < 8; ++e) {
    int lin = tid + 256*e;
    int p = lin >> 8, o = lin & 255;
    a1l[p][o] = A1[((size_t)ik*8 + p)*256 + o];
  }
  __syncthreads();
  int oq = tid >> 6, pq = tid & 63, p = pq >> 3, q = pq & 7;
  float2 acc = make_float2(0.f, 0.f);
  int o0 = oq*64;
  for (int o = o0; o < o0 + 64; ++o) cacc(acc, sl[q][o], a1l[p][o]);
  part[oq][pq] = acc;
  __syncthreads();
  if (oq == 0) {
    float2 a = part[0][pq], b = part[1][pq], c = part[2][pq], d = part[3][pq];
    acc.x = a.x + b.x + c.x + d.x;
    acc.y = a.y + b.y + c.y + d.y;
    Mt[(size_t)bid*64 + pq] = acc;
  }
}

// ---------------- out2[n,k,p,q] = sum_i Mt[n,i,k,p,q] res[i,k,p,q] ----------
__global__ __launch_bounds__(256) void k_out2(const float2* __restrict__ Mt,
    const float2* __restrict__ res, float2* __restrict__ out2) {
  int gid = blockIdx.x*256 + threadIdx.x;
  int pq = gid & 63, k = (gid >> 6) & 15, n = gid >> 10;
  float2 acc = make_float2(0.f, 0.f);
  for (int i = 0; i < 16; ++i)
    cacc(acc, Mt[((size_t)((n*16+i)*16 + k))*64 + pq], res[((size_t)(i*16+k))*64 + pq]);
  out2[((size_t)(n*16+k))*64 + pq] = acc;
}

// ---- build U (split bf16) : U[j,q,z] = sum_p out2[n,j,p,q] E1[j,kk,p,z] ----
__global__ __launch_bounds__(256) void k_Umm(const float2* __restrict__ out2,
    const float2* __restrict__ E1, unsigned* __restrict__ UH32,
    unsigned* __restrict__ UL32) {
  __shared__ float2 o2l[1024];        // [j][p][q]
  __shared__ float2 ul[64][129];      // [z-in-chunk][jq], padded
  int batch = blockIdx.x;             // n*16 + kk
  int kk = batch & 15, n = batch >> 4;
  int tid = threadIdx.x, lane = tid & 63, w = tid >> 6;
  for (int e = 0; e < 4; ++e) {
    int lin = tid + 256*e;
    int j = lin >> 6, pq = lin & 63;
    o2l[lin] = out2[((size_t)(n*16 + j))*64 + pq];
  }
  __syncthreads();
  for (int zc = 0; zc < 4; ++zc) {
    int z = zc*64 + lane;
    #pragma unroll
    for (int jj = 0; jj < 4; ++jj) {
      int j = w*4 + jj;
      float2 e1r[8];
      #pragma unroll
      for (int p = 0; p < 8; ++p)
        e1r[p] = E1[(((size_t)(j*16 + kk))*8 + p)*256 + z];
      #pragma unroll
      for (int q = 0; q < 8; ++q) {
        float2 acc = make_float2(0.f,0.f);
        #pragma unroll
        for (int p = 0; p < 8; ++p) cacc(acc, o2l[j*64 + p*8 + q], e1r[p]);
        ul[lane][j*8+q] = acc;
      }
    }
    __syncthreads();
    int jq = tid & 127, zh = tid >> 7;
    for (int it = 0; it < 32; ++it) {
      int zz = zh*32 + it;
      float2 u = ul[zz][jq];
      u16 hr, lr, hi_, li_;
      bf16split(u.x, hr, lr);
      bf16split(u.y, hi_, li_);
      size_t idx = ((size_t)batch*256 + zc*64 + zz)*128 + jq;
      UH32[idx] = (unsigned)hr | ((unsigned)hi_ << 16);
      UL32[idx] = (unsigned)lr | ((unsigned)li_ << 16);
    }
    __syncthreads();
  }
}

// ---- MFMA x2t GEMM + fused stats: X1[z][x] += (U x E2)/65536; partial sums -
__global__ __launch_bounds__(256) void k_x2tmm(const u16* __restrict__ UH,
    const u16* __restrict__ UL, const u16* __restrict__ EH,
    const u16* __restrict__ EL, float* __restrict__ X1,
    float2* __restrict__ statp) {
  __shared__ u16 Ah[128][40], Al[128][40], Bhs[128][40], Bls[128][40];
  __shared__ float rs[256], rq[256];
  int bid = blockIdx.x;               // batch*4 + mt*2 + nt
  int batch = bid >> 2, mt = (bid >> 1) & 1, nt = bid & 1;
  int kk = batch & 15;
  int tid = threadIdx.x;
  int lane = tid & 63, wid = tid >> 6, wr = wid >> 1, wc = wid & 1;
  int r2 = tid >> 1, h2 = tid & 1;
  const u16* uhrow = UH + ((size_t)(batch*256 + mt*128 + r2))*256 + h2*16;
  const u16* ulrow = UL + ((size_t)(batch*256 + mt*128 + r2))*256 + h2*16;
  const u16* ehrow = EH + ((size_t)(kk*256 + nt*128 + r2))*256 + h2*16;
  const u16* elrow = EL + ((size_t)(kk*256 + nt*128 + r2))*256 + h2*16;
  v4f acc[4][4];
  #pragma unroll
  for (int a = 0; a < 4; ++a)
    #pragma unroll
    for (int b = 0; b < 4; ++b) acc[a][b] = (v4f){0.f, 0.f, 0.f, 0.f};
  for (int kc = 0; kc < 8; ++kc) {
    {
      const uint4* pa = (const uint4*)(uhrow + (size_t)kc*32);
      uint4 a0 = pa[0], a1 = pa[1];
      *((uint4*)&Ah[r2][h2*16])     = a0;
      *((uint4*)&Ah[r2][h2*16 + 8]) = a1;
      const uint4* pb = (const uint4*)(ulrow + (size_t)kc*32);
      uint4 b0 = pb[0], b1 = pb[1];
      *((uint4*)&Al[r2][h2*16])     = b0;
      *((uint4*)&Al[r2][h2*16 + 8]) = b1;
      const uint4* pc = (const uint4*)(ehrow + (size_t)kc*32);
      uint4 c0 = pc[0], c1 = pc[1];
      *((uint4*)&Bhs[r2][h2*16])     = c0;
      *((uint4*)&Bhs[r2][h2*16 + 8]) = c1;
      const uint4* pd = (const uint4*)(elrow + (size_t)kc*32);
      uint4 d0 = pd[0], d1 = pd[1];
      *((uint4*)&Bls[r2][h2*16])     = d0;
      *((uint4*)&Bls[r2][h2*16 + 8]) = d1;
    }
    __syncthreads();
    v8s af_h[4], af_l[4];
    int c8 = (lane >> 4) * 8;
    #pragma unroll
    for (int fi = 0; fi < 4; ++fi) {
      int row = wr*64 + fi*16 + (lane & 15);
      af_h[fi] = *(const v8s*)&Ah[row][c8];
      af_l[fi] = *(const v8s*)&Al[row][c8];
    }
    #pragma unroll
    for (int fj = 0; fj < 4; ++fj) {
      int row = wc*64 + fj*16 + (lane & 15);
      v8s bh_f = *(const v8s*)&Bhs[row][c8];
      v8s bl_f = *(const v8s*)&Bls[row][c8];
      #pragma unroll
      for (int fi = 0; fi < 4; ++fi) {
        acc[fi][fj] = __builtin_amdgcn_mfma_f32_16x16x32_bf16(af_h[fi], bh_f, acc[fi][fj], 0, 0, 0);
        acc[fi][fj] = __builtin_amdgcn_mfma_f32_16x16x32_bf16(af_l[fi], bh_f, acc[fi][fj], 0, 0, 0);
        acc[fi][fj] = __builtin_amdgcn_mfma_f32_16x16x32_bf16(af_h[fi], bl_f, acc[fi][fj], 0, 0, 0);
      }
    }
    __syncthreads();
  }
  const float sc = 1.0f/65536.0f;
  float s = 0.f, s2 = 0.f;
  #pragma unroll
  for (int fi = 0; fi < 4; ++fi) {
    #pragma unroll
    for (int rr = 0; rr < 4; ++rr) {
      int z = mt*128 + wr*64 + fi*16 + (lane >> 4)*4 + rr;
      float* row = X1 + (size_t)batch*NPIX + (size_t)z*256 + nt*128 + wc*64 + (lane & 15);
      #pragma unroll
      for (int fj = 0; fj < 4; ++fj) {
        float nv = row[fj*16] + acc[fi][fj][rr] * sc;
        row[fj*16] = nv;
        s += nv; s2 += nv*nv;
      }
    }
  }
  rs[tid] = s; rq[tid] = s2;
  __syncthreads();
  for (int off = 128; off > 0; off >>= 1) {
    if (tid < off) { rs[tid] += rs[tid+off]; rq[tid] += rq[tid+off]; }
    __syncthreads();
  }
  if (tid == 0) statp[bid] = make_float2(rs[0], rq[0]);
}

// ---- fused out1 + row-iFFT: block = (o, k-pair), dbuf handoff --------------
__global__ __launch_bounds__(256) void k_out1g(const float2* __restrict__ alphaR,
    const float2* __restrict__ Tt, const float2* __restrict__ A2L,
    float2* __restrict__ out1) {
  __shared__ float2 tl[2][128];
  __shared__ float sre[2][4][256], sim[2][4][256];
  int d = blockIdx.x;                 // [0, 2048)
  int xcd = d & 7, idx = d >> 3;
  int o  = xcd*32 + (idx >> 3);
  int kh = idx & 7;
  int tid = threadIdx.x, x = tid;
  int lane = tid & 63, rowi = tid >> 6;
  {
    int kk = tid >> 7, rem = tid & 127;
    int i = rem >> 3, q = rem & 7;
    tl[kk][rem] = Tt[((size_t)((i*16 + 2*kh + kk)*8 + q))*256 + o];
  }
  // issue bp0/bp1 alpha loads early: latency hides under g-build
  const float2* arow = alphaR + (size_t)o*128*256 + x;
  float2 arA[16], arB[16];
  #pragma unroll
  for (int i = 0; i < 16; ++i) arA[i] = arow[(size_t)(0*16 + i)*256];
  #pragma unroll
  for (int i = 0; i < 16; ++i) arB[i] = arow[(size_t)(1*16 + i)*256];
  float2 tw[8];
  make_tw(+1.0f, lane, tw);
  __syncthreads();
  float2 g0[16], g1[16];
  #pragma unroll
  for (int i = 0; i < 16; ++i) {
    const float2* a2k0 = &A2L[((size_t)((i*16 + 2*kh + 0)*8))*256 + x];
    const float2* a2k1 = &A2L[((size_t)((i*16 + 2*kh + 1)*8))*256 + x];
    float2 acc0 = make_float2(0.f, 0.f), acc1 = make_float2(0.f, 0.f);
    #pragma unroll
    for (int q = 0; q < 8; ++q) {
      cacc(acc0, tl[0][i*8+q], a2k0[(size_t)q*256]);
      cacc(acc1, tl[1][i*8+q], a2k1[(size_t)q*256]);
    }
    g0[i] = acc0; g1[i] = acc1;
  }
  for (int bp = 0; bp < 4; ++bp) {
    int pb = bp & 1;
    float2 acc0 = make_float2(0.f,0.f), acc1 = acc0, acc2 = acc0, acc3 = acc0;
    #pragma unroll
    for (int i = 0; i < 16; ++i) {
      cacc(acc0, arA[i], g0[i]);
      cacc(acc1, arA[i], g1[i]);
      cacc(acc2, arB[i], g0[i]);
      cacc(acc3, arB[i], g1[i]);
    }
    sre[pb][0][x] = acc0.x; sim[pb][0][x] = acc0.y;
    sre[pb][1][x] = acc1.x; sim[pb][1][x] = acc1.y;
    sre[pb][2][x] = acc2.x; sim[pb][2][x] = acc2.y;
    sre[pb][3][x] = acc3.x; sim[pb][3][x] = acc3.y;
    __syncthreads();
    if (bp < 3) {
      int b0 = (bp+1)*2, b1 = b0 + 1;
      #pragma unroll
      for (int i = 0; i < 16; ++i) arA[i] = arow[(size_t)(b0*16 + i)*256];
      #pragma unroll
      for (int i = 0; i < 16; ++i) arB[i] = arow[(size_t)(b1*16 + i)*256];
    }
    float2 v0 = make_float2(sre[pb][rowi][lane],     sim[pb][rowi][lane]);
    float2 v1 = make_float2(sre[pb][rowi][64+lane],  sim[pb][rowi][64+lane]);
    float2 v2 = make_float2(sre[pb][rowi][128+lane], sim[pb][rowi][128+lane]);
    float2 v3 = make_float2(sre[pb][rowi][192+lane], sim[pb][rowi][192+lane]);
    ifft256_reg(v0, v1, v2, v3, lane, tw);
    int img = (bp*2 + (rowi >> 1))*16 + 2*kh + (rowi & 1);
    float2* op = out1 + ((size_t)img*256 + o)*256;
    nts2(&op[lane], v0); nts2(&op[64+lane], v1);
    nts2(&op[128+lane], v2); nts2(&op[192+lane], v3);
  }
}

// ---------------- final: inorm(x1pre) + w0conv(v) -> fc1 -> sin -> fc2 ------
__global__ __launch_bounds__(256) void k_final(const float* __restrict__ x,
    const float* __restrict__ x1pre, const float2* __restrict__ stats2,
    const float* __restrict__ fc0w, const float* __restrict__ fc0b,
    const float* __restrict__ w0w, const float* __restrict__ w0b,
    const float* __restrict__ fc1w, const float* __restrict__ fc1b,
    const float* __restrict__ fc2w, const float* __restrict__ fc2b,
    float* __restrict__ out) {
  __shared__ float s_fc1w[2048], s_fc1b[128], s_fc2w[384], s_w0w[256], s_w0b[16], s_fc2b[3];
  int tid = threadIdx.x;
  for (int e = 0; e < 8; ++e) s_fc1w[tid + 256*e] = fc1w[tid + 256*e];
  if (tid < 128) s_fc1b[tid] = fc1b[tid];
  for (int e = 0; e < 2; ++e) { int q = tid + 256*e; if (q < 384) s_fc2w[q] = fc2w[q]; }
  s_w0w[tid] = w0w[tid];
  if (tid < 16) s_w0b[tid] = w0b[tid];
  if (tid < 3)  s_fc2b[tid] = fc2b[tid];
  __syncthreads();

  int bid = blockIdx.x;               // b*256 + h
  int hh = bid & 255, b = bid >> 8;
  int ww = tid;
  size_t pix = (size_t)hh*256 + ww;
  float xc0 = x[((size_t)b*3 + 0)*NPIX + pix];
  float xc1 = x[((size_t)b*3 + 1)*NPIX + pix];
  float xc2 = x[((size_t)b*3 + 2)*NPIX + pix];
  float gx = hh*(1.0f/255.0f), gy = ww*(1.0f/255.0f);
  float v[16], x1n[16], uo[16];
  #pragma unroll
  for (int k = 0; k < 16; ++k)
    v[k] = fc0b[k] + xc0*fc0w[k] + xc1*fc0w[16+k] + xc2*fc0w[32+k] + gx*fc0w[48+k] + gy*fc0w[64+k];
  #pragma unroll
  for (int k = 0; k < 16; ++k) {
    float2 st = stats2[b*16 + k];
    float xv = x1pre[((size_t)(b*16 + k))*NPIX + pix];
    x1n[k] = (xv - st.x)*st.y;
  }
  #pragma unroll
  for (int o = 0; o < 16; ++o) {
    float acc = s_w0b[o];
    #pragma unroll
    for (int k = 0; k < 16; ++k) acc = fmaf(v[k], s_w0w[o*16+k], acc);
    uo[o] = acc + x1n[o];
  }
  float o0 = 0.f, o1 = 0.f, o2 = 0.f;
  for (int jj = 0; jj < 128; ++jj) {
    float t = s_fc1b[jj];
    #pragma unroll
    for (int k = 0; k < 16; ++k) t = fmaf(uo[k], s_fc1w[k*128 + jj], t);
    float s = __sinf(t);
    o0 = fmaf(s, s_fc2w[jj*3+0], o0);
    o1 = fmaf(s, s_fc2w[jj*3+1], o1);
    o2 = fmaf(s, s_fc2w[jj*3+2], o2);
  }
  out[((size_t)b*3 + 0)*NPIX + pix] = o0 + s_fc2b[0];
  out[((size_t)b*3 + 1)*NPIX + pix] = o1 + s_fc2b[1];
  out[((size_t)b*3 + 2)*NPIX + pix] = o2 + s_fc2b[2];
}

// ---------------------------------------------------------------------------
extern "C" void kernel_launch(void* const* d_in, const int* in_sizes, int n_in,
                              void* d_out, int out_size, void* d_ws, size_t ws_size,
                              hipStream_t stream) {
  const float*  x    = (const float*)d_in[0];
  const float*  fc0w = (const float*)d_in[1];
  const float*  fc0b = (const float*)d_in[2];
  const float2* p1   = (const float2*)d_in[3];
  const float2* p2   = (const float2*)d_in[4];
  const float2* res  = (const float2*)d_in[5];
  const float*  w0w  = (const float*)d_in[6];
  const float*  w0b  = (const float*)d_in[7];
  const float*  fc1w = (const float*)d_in[8];
  const float*  fc1b = (const float*)d_in[9];
  const float*  fc2w = (const float*)d_in[10];
  const float*  fc2b = (const float*)d_in[11];
  const float*  txv  = (const float*)d_in[12];
  const float*  tyv  = (const float*)d_in[13];
  float* out = (float*)d_out;

  // workspace layout (bytes); NEED == proven-safe 252,774,400
  const size_t OFF_A1   = 0;            // 4 MiB
  const size_t OFF_A2T  = 4194304;      // 4 MiB
  const size_t OFF_E1   = 8388608;      // 4 MiB
  const size_t OFF_E2   = 12582912;     // 4 MiB
  const size_t OFF_ST1  = 16777216;
  const size_t OFF_ST2  = 16778240;
  const size_t OFF_OUT2 = 16779264;     // 64 KiB
  const size_t OFF_MT   = 16844800;     // 1 MiB (Mt; later x2tmm stat partials)
  const size_t OFF_S    = 17893376;     // 32 MiB (stats-v partials; S; later UH+UL)
  const size_t OFF_X1   = 51447808;     // 32 MiB (Tt early; X1 later)
  const size_t OFF_A    = 85002240;     // 64 MiB (row-fft; out1 row-ifft'd)
  const size_t OFF_B    = 152111104;    // 64 MiB (alphaR o-major)
  const size_t OFF_G    = 219219968;    // 32 MiB (A2L 4 + BH 4 + BL 4 + EH 2 + EL 2)
  const size_t NEED     = 252774400;
  if (ws_size < NEED) return;
  char* ws = (char*)d_ws;
  float2* A1  = (float2*)(ws + OFF_A1);
  float2* A2T = (float2*)(ws + OFF_A2T);
  float2* E1  = (float2*)(ws + OFF_E1);
  float2* E2  = (float2*)(ws + OFF_E2);
  float2* st1 = (float2*)(ws + OFF_ST1);
  float2* st2 = (float2*)(ws + OFF_ST2);
  float2* o2b = (float2*)(ws + OFF_OUT2);
  float2* Mt  = (float2*)(ws + OFF_MT);
  float2* Sb  = (float2*)(ws + OFF_S);
  float2* Tt  = (float2*)(ws + OFF_X1);
  float*  X1  = (float*)(ws + OFF_X1);
  float2* Ab  = (float2*)(ws + OFF_A);
  float2* Bb  = (float2*)(ws + OFF_B);
  float2* A2L = (float2*)(ws + OFF_G);
  u16*    BH  = (u16*)(ws + OFF_G + 4194304);
  u16*    BL  = (u16*)(ws + OFF_G + 8388608);
  unsigned* EH32 = (unsigned*)(ws + OFF_G + 12582912);   // 2 MiB
  unsigned* EL32 = (unsigned*)(ws + OFF_G + 14680064);   // 2 MiB
  unsigned* UH32 = (unsigned*)(ws + OFF_S);              // 16 MiB (S dead after k_Mt)
  unsigned* UL32 = (unsigned*)(ws + OFF_S + 16777216);   // 16 MiB

  k_setup  <<<2048, 256, 0, stream>>>(p1, p2, txv, tyv, A1, A2T, A2L, E1, E2);
  k_B      <<<128, 256, 0, stream>>>(A2T, BH, BL);
  k_E2s    <<<16, 256, 0, stream>>>(E2, EH32, EL32);
  k_T      <<<256, 256, 0, stream>>>(res, A1, Tt);
  k_stats_v_part<<<1024, 256, 0, stream>>>(x, fc0w, fc0b, Sb);
  k_stats_fin   <<<1, 256, 0, stream>>>(Sb, st1, 128, 8);
  // forward fft2
  k_fft_v  <<<8192, 256, 0, stream>>>(x, fc0w, fc0b, st1, Ab);
  k_fft_colR<<<2048, 256, 0, stream>>>(Ab, Bb);                 // Bb = alphaR
  // pole-residue spectral sums (MFMA)
  k_Smm    <<<512, 256, 0, stream>>>(Bb, BH, BL, (float*)Sb);
  k_Mt     <<<2048, 256, 0, stream>>>(Sb, A1, Mt);
  k_out2   <<<32, 256, 0, stream>>>(Mt, res, o2b);
  // transient: U build (into dead S region, split bf16)
  k_Umm    <<<128, 256, 0, stream>>>(o2b, E1, UH32, UL32);
  // fused out1 + row-iFFT
  k_out1g  <<<2048, 256, 0, stream>>>(Bb, Tt, A2L, Ab);
  // inverse column FFT -> X1
  k_ifft_col_real<<<2048, 256, 0, stream>>>(Ab, X1, 1.0f/65536.0f);
  // transient GEMM: X1 += U x E2 / 65536, with fused stats partials (in Mt)
  k_x2tmm  <<<512, 256, 0, stream>>>((const u16*)UH32, (const u16*)UL32,
                                     (const u16*)EH32, (const u16*)EL32, X1, Mt);
  k_stats_fin   <<<1, 256, 0, stream>>>(Mt, st2, 128, 4);
  k_final  <<<2048, 256, 0, stream>>>(x, X1, st2, fc0w, fc0b,
                                      w0w, w0b, fc1w, fc1b, fc2w, fc2b, out);
}